// Round 14
// baseline (183.840 us; speedup 1.0000x reference)
//
#include <hip/hip_runtime.h>
#include <hip/hip_bf16.h>

#define DB 8
#define DN 1024
#define DP 1024
#define DC 256
#define DNS 32
#define DBP (DB * DP)
#define K1 288   // padded GEMM1 K (256 feats + 3 gx + 29 zeros)
#define K2 256
#define XS 296   // x_lds row stride in bf16 elems (592 B; 148 dwords == 20 mod 32)
#define YS 258   // epilogue y-tile row stride in bf16 (129 dwords == 1 mod 32)
#define ROWS 128 // 4 bp per block
#define NG (DBP / 4)
#define NK1 (K1 / 32)  // 9
#define NK2 (K2 / 32)  // 8

constexpr float kRadius = 0.05f;
constexpr float kR2 = kRadius * kRadius;
constexpr float kHmin = -0.02f;
constexpr float kHmax = 0.04f;
constexpr float kEps = 1e-5f;
constexpr float kInvCnt = 1.0f / (float)(DB * DP * DNS);

typedef __bf16 bf16x8 __attribute__((ext_vector_type(8)));
typedef float f32x4 __attribute__((ext_vector_type(4)));
static_assert(sizeof(bf16x8) == 16, "bf16x8 must be 16B");

// ---- workspace layout (in floats) ----
constexpr size_t OF_FEATST = 0;                                   // B*N*C bf16
constexpr size_t OF_W1B  = OF_FEATST + (size_t)DB * DN * DC / 2;  // DC*K1 bf16
constexpr size_t OF_W2B  = OF_W1B + (size_t)DC * K1 / 2;          // DC*K2 bf16
constexpr size_t OF_IDX  = OF_W2B + (size_t)DC * K2 / 2;          // BP*NS int32
constexpr size_t OF_GX   = OF_IDX + (size_t)DBP * DNS;            // BP*NS*3
constexpr size_t OF_PART = OF_GX + (size_t)DBP * DNS * 3;         // NG*C*2
constexpr size_t OF_YMAX = OF_PART + (size_t)DBP * DC * 2;        // BP*C
constexpr size_t OF_YMIN = OF_YMAX + (size_t)DBP * DC;            // BP*C
constexpr size_t OF_BN1  = OF_YMIN + (size_t)DBP * DC;            // 512
constexpr size_t OF_BN2  = OF_BN1 + 512;                          // 512
// ---- point-factored stats scratch ----
constexpr size_t OF_CNTZ = OF_BN2 + 512;                          // 64*DN
constexpr size_t OF_GWZ  = OF_CNTZ + (size_t)64 * DN;             // 64*3*DN
constexpr size_t OF_GG64 = OF_GWZ + (size_t)64 * 3 * DN;          // 64*16
constexpr size_t OF_YPRT = OF_GG64 + 1024;                        // 64*DC*2

__device__ inline ushort f2b(float x) {
  union { __hip_bfloat16 h; ushort u; } c;
  c.h = __float2bfloat16(x);
  return c.u;
}
__device__ inline float b2f(ushort u) {
  union { uint u; float f; } c;
  c.u = (uint)u << 16;
  return c.f;
}

// ---------------------------------------------------------------------------
// fused pre-pass: [0,2048) transpose feats; [2048,2336) W1 prep; [2336,2592)
// W2 prep; [2592,4640) cylinder query (4 bp per block, one per wave).
__global__ __launch_bounds__(256)
void k_prep(const float* __restrict__ f, uint* __restrict__ ftb,
            const float* __restrict__ W1, ushort* __restrict__ W1b,
            const float* __restrict__ W2, ushort* __restrict__ W2b,
            const float* __restrict__ xyz, const float* __restrict__ rot,
            int* __restrict__ idxp, float* __restrict__ gxp) {
  __shared__ float t[32][33];
  __shared__ int sidx[4][DNS];
  __shared__ float srot[4][9], sc[4][3];
  int blk = blockIdx.x;
  int tid = threadIdx.x;
  if (blk < 2048) {
    int ct = blk & 7, nt = (blk >> 3) & 31, b = blk >> 8;
    int tx = tid & 31, ty = tid >> 5;
#pragma unroll
    for (int k = 0; k < 4; ++k) {
      int c = ct * 32 + ty + k * 8;
      t[ty + k * 8][tx] = f[((size_t)b * DC + c) * DN + nt * 32 + tx];
    }
    __syncthreads();
    uint* dst = ftb + (size_t)b * DN * (DC / 2);
#pragma unroll
    for (int it = 0; it < 2; ++it) {
      int idx = it * 256 + tid;
      int nl = idx >> 4, cp = idx & 15;
      uint v = (uint)f2b(t[2 * cp][nl]) | ((uint)f2b(t[2 * cp + 1][nl]) << 16);
      dst[(size_t)(nt * 32 + nl) * (DC / 2) + ct * 16 + cp] = v;
    }
  } else if (blk < 2336) {
    int gid = (blk - 2048) * 256 + tid;
    if (gid < DC * K1) {
      int o = gid / K1, kp = gid - o * K1;
      float v = 0.f;
      if (kp < 256) v = W1[o * 259 + 3 + kp];
      else if (kp < 259) v = W1[o * 259 + (kp - 256)];
      W1b[gid] = f2b(v);
    }
  } else if (blk < 2592) {
    int gid = (blk - 2336) * 256 + tid;
    if (gid < DC * K2) W2b[gid] = f2b(W2[gid]);
  } else {
    int wv = tid >> 6;
    int lane = tid & 63;
    int bp = (blk - 2592) * 4 + wv;
    int b = bp >> 10;
    if (lane < DNS) sidx[wv][lane] = 0;
    if (lane < 9) srot[wv][lane] = rot[(size_t)bp * 9 + lane];
    if (lane < 3) sc[wv][lane] = xyz[(size_t)bp * 3 + lane];
    float r00 = srot[wv][0], r01 = srot[wv][1], r02 = srot[wv][2];
    float r10 = srot[wv][3], r11 = srot[wv][4], r12 = srot[wv][5];
    float r20 = srot[wv][6], r21 = srot[wv][7], r22 = srot[wv][8];
    float cx = sc[wv][0], cy = sc[wv][1], cz = sc[wv][2];
    const float* xb = xyz + (size_t)b * DN * 3;
    int cnt = 0;
    for (int ch = 0; ch < DN / 64 && cnt < DNS; ++ch) {
      int n = ch * 64 + lane;
      float dx = xb[n * 3 + 0] - cx, dy = xb[n * 3 + 1] - cy, dz = xb[n * 3 + 2] - cz;
      float lx = dx * r00 + dy * r10 + dz * r20;
      float ly = dx * r01 + dy * r11 + dz * r21;
      float lz = dx * r02 + dy * r12 + dz * r22;
      bool m = (ly * ly + lz * lz < kR2) && (lx > kHmin) && (lx < kHmax);
      unsigned long long bal = __ballot(m);
      int rank = cnt + __popcll(bal & ((1ull << lane) - 1ull));
      if (m && rank < DNS) sidx[wv][rank] = n;
      cnt += __popcll(bal);
    }
    if (lane < DNS) {
      int j = sidx[wv][lane];
      idxp[(size_t)bp * DNS + lane] = j;
      float gx = (xb[j * 3 + 0] - cx) / kRadius;
      float gy = (xb[j * 3 + 1] - cy) / kRadius;
      float gz = (xb[j * 3 + 2] - cz) / kRadius;
      float* gp = gxp + ((size_t)bp * DNS + lane) * 3;
      gp[0] = gx * r00 + gy * r10 + gz * r20;
      gp[1] = gx * r01 + gy * r11 + gz * r21;
      gp[2] = gx * r02 + gy * r12 + gz * r22;
    }
  }
}

// ---------------------------------------------------------------------------
// per-point counts + weighted gx sums via LDS histogram, plain-stored into
// per-block slices. 64 blocks x 256. gg64[blk*16+v]: v=0..5 2nd moments, 6..8 sums.
__global__ __launch_bounds__(256)
void k_count(const int* __restrict__ idxp, const float* __restrict__ gxp,
             float* __restrict__ cntz, float* __restrict__ gwz,
             float* __restrict__ gg64) {
  __shared__ float h0[DN], h1[DN], h2[DN], h3[DN];
  int t = threadIdx.x;
  int blk = blockIdx.x;
  int b = blk >> 3, s = blk & 7;
  for (int i = t; i < DN; i += 256) {
    h0[i] = 0.f; h1[i] = 0.f; h2[i] = 0.f; h3[i] = 0.f;
  }
  __syncthreads();
  float p[9] = {0.f, 0.f, 0.f, 0.f, 0.f, 0.f, 0.f, 0.f, 0.f};
#pragma unroll
  for (int r = 0; r < 16; ++r) {
    int sid = blk * 4096 + r * 256 + t;
    int j = idxp[sid];
    const float* g = gxp + (size_t)sid * 3;
    float g0 = g[0], g1 = g[1], g2 = g[2];
    atomicAdd(&h0[j], 1.f);
    atomicAdd(&h1[j], g0);
    atomicAdd(&h2[j], g1);
    atomicAdd(&h3[j], g2);
    p[0] += g0 * g0; p[1] += g0 * g1; p[2] += g0 * g2;
    p[3] += g1 * g1; p[4] += g1 * g2; p[5] += g2 * g2;
    p[6] += g0; p[7] += g1; p[8] += g2;
  }
  __syncthreads();
  for (int i = t; i < DN; i += 256) {
    cntz[((size_t)b * 8 + s) * DN + i] = h0[i];
    gwz[(((size_t)b * 8 + s) * 3 + 0) * DN + i] = h1[i];
    gwz[(((size_t)b * 8 + s) * 3 + 1) * DN + i] = h2[i];
    gwz[(((size_t)b * 8 + s) * 3 + 2) * DN + i] = h3[i];
  }
  __shared__ float sgg[4][9];
#pragma unroll
  for (int v = 0; v < 9; ++v) {
    float sv = p[v];
#pragma unroll
    for (int m = 1; m < 64; m <<= 1) sv += __shfl_xor(sv, m, 64);
    if ((t & 63) == 0) sgg[t >> 6][v] = sv;
  }
  __syncthreads();
  if (t < 9) gg64[blk * 16 + t] = sgg[0][t] + sgg[1][t] + sgg[2][t] + sgg[3][t];
}

// ---------------------------------------------------------------------------
// Yf = W1_feat x feats over unique points (K=256, no gather), fused weighted
// stats. 64 blocks x 256 thr.
__global__ __launch_bounds__(256)
void k_ygemm(const uint4* __restrict__ ftb, const ushort* __restrict__ W1b,
             const float* __restrict__ W1, const float* __restrict__ cntz,
             const float* __restrict__ gwz, float2* __restrict__ ypart) {
  __shared__ ushort x_lds[ROWS * XS];
  __shared__ float c_lds[ROWS];
  __shared__ float g_lds[3][ROWS];
  __shared__ float wg_lds[DC][3];

  const int nb = blockIdx.x;       // 0..63
  const int b = nb >> 3;
  const int n0 = (nb & 7) * ROWS;
  const int tid = threadIdx.x;
  const int lane = tid & 63;
  const int wv = tid >> 6;
  const int l15 = lane & 15;
  const int l4 = lane >> 4;

  {
    const uint4* src = ftb + ((size_t)b * DN + n0) * (DC / 8);
    for (int idx = tid; idx < ROWS * 32; idx += 256) {
      int rrow = idx >> 5, col = idx & 31;
      ((uint4*)(x_lds + (size_t)rrow * XS))[col] = src[rrow * 32 + col];
    }
  }
  if (tid < ROWS) {
    float c = 0.f, g0 = 0.f, g1 = 0.f, g2 = 0.f;
#pragma unroll
    for (int s = 0; s < 8; ++s) {
      c += cntz[((size_t)b * 8 + s) * DN + n0 + tid];
      g0 += gwz[(((size_t)b * 8 + s) * 3 + 0) * DN + n0 + tid];
      g1 += gwz[(((size_t)b * 8 + s) * 3 + 1) * DN + n0 + tid];
      g2 += gwz[(((size_t)b * 8 + s) * 3 + 2) * DN + n0 + tid];
    }
    c_lds[tid] = c; g_lds[0][tid] = g0; g_lds[1][tid] = g1; g_lds[2][tid] = g2;
  }
  {
    wg_lds[tid][0] = W1[tid * 259 + 0];
    wg_lds[tid][1] = W1[tid * 259 + 1];
    wg_lds[tid][2] = W1[tid * 259 + 2];
  }
  __syncthreads();

  f32x4 acc[4][8];
#pragma unroll
  for (int t = 0; t < 4; ++t)
#pragma unroll
    for (int st = 0; st < 8; ++st)
#pragma unroll
      for (int r = 0; r < 4; ++r) acc[t][st][r] = 0.f;

  const int o0 = wv * 64;
  const ushort* xbase = x_lds + (size_t)l15 * XS + l4 * 8;
  {
    const ushort* wrow[4];
#pragma unroll
    for (int t = 0; t < 4; ++t)
      wrow[t] = W1b + (size_t)(o0 + t * 16 + l15) * K1 + l4 * 8;
#pragma unroll
    for (int ks = 0; ks < 8; ++ks) {
      bf16x8 bx[8], aw[4];
#pragma unroll
      for (int st = 0; st < 8; ++st)
        bx[st] = *(const bf16x8*)(xbase + (size_t)st * 16 * XS + ks * 32);
#pragma unroll
      for (int t = 0; t < 4; ++t) aw[t] = *(const bf16x8*)(wrow[t] + ks * 32);
#pragma unroll
      for (int st = 0; st < 8; ++st)
#pragma unroll
        for (int t = 0; t < 4; ++t)
          acc[t][st] = __builtin_amdgcn_mfma_f32_16x16x32_bf16(aw[t], bx[st],
                                                               acc[t][st], 0, 0, 0);
    }
  }

  float cn[8], h0[8], h1[8], h2[8];
#pragma unroll
  for (int st = 0; st < 8; ++st) {
    int n = st * 16 + l15;
    cn[st] = c_lds[n]; h0[st] = g_lds[0][n]; h1[st] = g_lds[1][n]; h2[st] = g_lds[2][n];
  }
#pragma unroll
  for (int t = 0; t < 4; ++t) {
#pragma unroll
    for (int r = 0; r < 4; ++r) {
      int o = o0 + t * 16 + l4 * 4 + r;
      float wg0 = wg_lds[o][0], wg1 = wg_lds[o][1], wg2 = wg_lds[o][2];
      float s = 0.f, q = 0.f;
#pragma unroll
      for (int st = 0; st < 8; ++st) {
        float Y = acc[t][st][r];
        float h = wg0 * h0[st] + wg1 * h1[st] + wg2 * h2[st];
        s = fmaf(cn[st], Y, s);
        q += cn[st] * Y * Y + 2.f * Y * h;
      }
#pragma unroll
      for (int m = 1; m < 16; m <<= 1) {
        s += __shfl_xor(s, m, 64);
        q += __shfl_xor(q, m, 64);
      }
      if (l15 == 0) ypart[(size_t)nb * DC + o] = make_float2(s, q);
    }
  }
}

// ---------------------------------------------------------------------------
__global__ __launch_bounds__(256)
void k_bn1f(const float2* __restrict__ ypart, const float* __restrict__ gg64,
            const float* __restrict__ W1, const float* __restrict__ gam,
            const float* __restrict__ bet, float* __restrict__ bn) {
  __shared__ float ggs[9];
  int t = threadIdx.x;
  if (t < 9) {
    float s = 0.f;
    for (int blk = 0; blk < 64; ++blk) s += gg64[blk * 16 + t];
    ggs[t] = s;
  }
  __syncthreads();
  float s = 0.f, q = 0.f;
  for (int nb = 0; nb < 64; ++nb) {
    float2 v = ypart[(size_t)nb * DC + t];
    s += v.x; q += v.y;
  }
  float wg0 = W1[t * 259 + 0], wg1 = W1[t * 259 + 1], wg2 = W1[t * 259 + 2];
  s += wg0 * ggs[6] + wg1 * ggs[7] + wg2 * ggs[8];
  q += wg0 * wg0 * ggs[0] + 2.f * wg0 * wg1 * ggs[1] + 2.f * wg0 * wg2 * ggs[2] +
       wg1 * wg1 * ggs[3] + 2.f * wg1 * wg2 * ggs[4] + wg2 * wg2 * ggs[5];
  float mu = s * kInvCnt;
  float var = q * kInvCnt - mu * mu;
  var = var < 0.f ? 0.f : var;
  float sc = gam[t] * rsqrtf(var + kEps);
  bn[t] = sc;
  bn[DC + t] = bet[t] - mu * sc;
}

// ---------------------------------------------------------------------------
// MFMA GEMM over 4 bp per block, 16x16x32 bf16 — 512 threads / 8 waves.
// Wave w owns 4 o-tiles (o0 = (w&3)*64) x 4 s-tiles (s0 = (w>>2)*64):
// halves per-wave B LDS reads vs the 8-way o-split (round-13 LDS-bound fix).
// D layout: col = lane&15 (=s), row = (lane>>4)*4 + reg (=o).
__global__ __launch_bounds__(512, 4)
void k_gemm_full(const uint4* __restrict__ ftb, const ushort* __restrict__ W1b,
                 const ushort* __restrict__ W2b, const int* __restrict__ idxp,
                 const float* __restrict__ gxp, const float* __restrict__ bn1,
                 float2* __restrict__ part, float* __restrict__ ymax,
                 float* __restrict__ ymin) {
  __shared__ ushort x_lds[ROWS * XS];   // 75776 B; also holds 128x258 y tile
  __shared__ float bn_lds[2 * DC];

  const int grp = blockIdx.x;           // 0..NG-1
  const int bp0 = grp * 4;
  const int b = bp0 >> 10;
  const int tid = threadIdx.x;          // 0..511
  const int lane = tid & 63;
  const int wv = tid >> 6;              // 0..7
  const int l15 = lane & 15;
  const int l4 = lane >> 4;

  bn_lds[tid] = bn1[tid];               // 512 threads == 2*DC

  // ---- gather feats: 8 threads/row, 128-B coalesced segments, 2 passes ----
  {
    int q = tid & 7;
#pragma unroll
    for (int rep = 0; rep < 2; ++rep) {
      int s = (tid >> 3) + rep * 64;
      int j = idxp[(size_t)bp0 * DNS + s];
      const uint4* src = ftb + (size_t)(b * DN + j) * (DC / 8);
      uint4* dst = (uint4*)(x_lds + (size_t)s * XS);
#pragma unroll
      for (int k = 0; k < 4; ++k) dst[q + 8 * k] = src[q + 8 * k];
    }
  }
  // ---- gx channels at k=256..258, zeros to 287 ----
  if (tid < ROWS) {
    const float* g = gxp + ((size_t)bp0 * DNS + tid) * 3;
    uint a0 = (uint)f2b(g[0]) | ((uint)f2b(g[1]) << 16);
    uint a1 = (uint)f2b(g[2]);
    uint4* drow = (uint4*)(x_lds + (size_t)tid * XS + 256);
    drow[0] = make_uint4(a0, a1, 0u, 0u);
    drow[1] = make_uint4(0u, 0u, 0u, 0u);
    drow[2] = make_uint4(0u, 0u, 0u, 0u);
    drow[3] = make_uint4(0u, 0u, 0u, 0u);
  }
  __syncthreads();

  f32x4 acc[4][4];
#pragma unroll
  for (int t = 0; t < 4; ++t)
#pragma unroll
    for (int st = 0; st < 4; ++st)
#pragma unroll
      for (int r = 0; r < 4; ++r) acc[t][st][r] = 0.f;

  const int o0 = (wv & 3) * 64;
  const int s0 = (wv >> 2) * 64;
  const ushort* xbase = x_lds + (size_t)(s0 + l15) * XS + l4 * 8;

  // ---- GEMM1: K = 288, 9 K-steps of 32; A prefetched one step ahead ----
  {
    const ushort* wrow[4];
#pragma unroll
    for (int t = 0; t < 4; ++t)
      wrow[t] = W1b + (size_t)(o0 + t * 16 + l15) * K1 + l4 * 8;
    bf16x8 aw[4];
#pragma unroll
    for (int t = 0; t < 4; ++t) aw[t] = *(const bf16x8*)(wrow[t]);
#pragma unroll
    for (int ks = 0; ks < NK1; ++ks) {
      bf16x8 bx[4];
#pragma unroll
      for (int st = 0; st < 4; ++st)
        bx[st] = *(const bf16x8*)(xbase + (size_t)st * 16 * XS + ks * 32);
      bf16x8 an[4];
      if (ks + 1 < NK1) {
#pragma unroll
        for (int t = 0; t < 4; ++t)
          an[t] = *(const bf16x8*)(wrow[t] + (ks + 1) * 32);
      }
      __builtin_amdgcn_s_setprio(1);
#pragma unroll
      for (int st = 0; st < 4; ++st)
#pragma unroll
        for (int t = 0; t < 4; ++t)
          acc[t][st] = __builtin_amdgcn_mfma_f32_16x16x32_bf16(aw[t], bx[st],
                                                               acc[t][st], 0, 0, 0);
      __builtin_amdgcn_s_setprio(0);
      if (ks + 1 < NK1) {
#pragma unroll
        for (int t = 0; t < 4; ++t) aw[t] = an[t];
      }
    }
  }

  // ---- bn1 + relu -> x2 (bf16) back into x_lds[s][o] (stride XS) ----
  __syncthreads();  // all GEMM1 LDS reads complete before overwrite
#pragma unroll
  for (int t = 0; t < 4; ++t) {
    int ob = o0 + t * 16 + l4 * 4;
    float sc0 = bn_lds[ob + 0], sh0 = bn_lds[DC + ob + 0];
    float sc1 = bn_lds[ob + 1], sh1 = bn_lds[DC + ob + 1];
    float sc2 = bn_lds[ob + 2], sh2 = bn_lds[DC + ob + 2];
    float sc3 = bn_lds[ob + 3], sh3 = bn_lds[DC + ob + 3];
#pragma unroll
    for (int st = 0; st < 4; ++st) {
      float v0 = fmaxf(fmaf(acc[t][st][0], sc0, sh0), 0.f);
      float v1 = fmaxf(fmaf(acc[t][st][1], sc1, sh1), 0.f);
      float v2 = fmaxf(fmaf(acc[t][st][2], sc2, sh2), 0.f);
      float v3 = fmaxf(fmaf(acc[t][st][3], sc3, sh3), 0.f);
      uint2 pk = make_uint2((uint)f2b(v0) | ((uint)f2b(v1) << 16),
                            (uint)f2b(v2) | ((uint)f2b(v3) << 16));
      int s = s0 + st * 16 + l15;
      *(uint2*)(x_lds + (size_t)s * XS + ob) = pk;
      acc[t][st][0] = 0.f; acc[t][st][1] = 0.f;
      acc[t][st][2] = 0.f; acc[t][st][3] = 0.f;
    }
  }
  __syncthreads();

  // ---- GEMM2: K = 256, 8 K-steps ----
  {
    const ushort* wrow[4];
#pragma unroll
    for (int t = 0; t < 4; ++t)
      wrow[t] = W2b + (size_t)(o0 + t * 16 + l15) * K2 + l4 * 8;
    bf16x8 aw[4];
#pragma unroll
    for (int t = 0; t < 4; ++t) aw[t] = *(const bf16x8*)(wrow[t]);
#pragma unroll
    for (int ks = 0; ks < NK2; ++ks) {
      bf16x8 bx[4];
#pragma unroll
      for (int st = 0; st < 4; ++st)
        bx[st] = *(const bf16x8*)(xbase + (size_t)st * 16 * XS + ks * 32);
      bf16x8 an[4];
      if (ks + 1 < NK2) {
#pragma unroll
        for (int t = 0; t < 4; ++t)
          an[t] = *(const bf16x8*)(wrow[t] + (ks + 1) * 32);
      }
      __builtin_amdgcn_s_setprio(1);
#pragma unroll
      for (int st = 0; st < 4; ++st)
#pragma unroll
        for (int t = 0; t < 4; ++t)
          acc[t][st] = __builtin_amdgcn_mfma_f32_16x16x32_bf16(aw[t], bx[st],
                                                               acc[t][st], 0, 0, 0);
      __builtin_amdgcn_s_setprio(0);
      if (ks + 1 < NK2) {
#pragma unroll
        for (int t = 0; t < 4; ++t) aw[t] = an[t];
      }
    }
  }

  // ---- y2 -> bf16 [s][o] tile, then per-o column stats + per-bp max/min ----
  __syncthreads();
#pragma unroll
  for (int t = 0; t < 4; ++t) {
    int ob = o0 + t * 16 + l4 * 4;
#pragma unroll
    for (int st = 0; st < 4; ++st) {
      uint2 pk = make_uint2(
          (uint)f2b(acc[t][st][0]) | ((uint)f2b(acc[t][st][1]) << 16),
          (uint)f2b(acc[t][st][2]) | ((uint)f2b(acc[t][st][3]) << 16));
      int s = s0 + st * 16 + l15;
      *(uint2*)(x_lds + (size_t)s * YS + ob) = pk;
    }
  }
  __syncthreads();
  {
    // partial-sum scratch in the free tail of x_lds (bytes 66048..70144)
    float* redp = (float*)(x_lds + (size_t)ROWS * YS);
    int o = tid & 255, half = tid >> 8;   // half: rows [half*64, half*64+64)
    const ushort* col = x_lds + o;
    float s = 0.f, q = 0.f;
#pragma unroll
    for (int p2 = 0; p2 < 2; ++p2) {
      int p = half * 2 + p2;              // bp index 0..3
      float mx = -3.4e38f, mn = 3.4e38f;
#pragma unroll 8
      for (int i = 0; i < DNS; ++i) {
        float v = b2f(col[(size_t)(p * DNS + i) * YS]);
        s += v; q += v * v;
        mx = fmaxf(mx, v); mn = fminf(mn, v);
      }
      ymax[(size_t)(bp0 + p) * DC + o] = mx;
      ymin[(size_t)(bp0 + p) * DC + o] = mn;
    }
    redp[half * 256 + o] = s;
    redp[512 + half * 256 + o] = q;
    __syncthreads();
    if (tid < 256) {
      float ss = redp[tid] + redp[256 + tid];
      float qq = redp[512 + tid] + redp[768 + tid];
      part[(size_t)grp * DC + tid] = make_float2(ss, qq);
    }
  }
}

// ---------------------------------------------------------------------------
__global__ void k_reduce_bn(const float* __restrict__ part, const float* __restrict__ gam,
                            const float* __restrict__ bet, float* __restrict__ bn) {
  int o = blockIdx.x, tid = threadIdx.x;
  __shared__ float ss[256], sq[256];
  float s = 0.f, q = 0.f;
  const float2* pp = (const float2*)part;
  for (int g = tid; g < NG; g += 256) {
    float2 v = pp[(size_t)g * DC + o];
    s += v.x; q += v.y;
  }
  ss[tid] = s; sq[tid] = q;
  __syncthreads();
  for (int w = 128; w > 0; w >>= 1) {
    if (tid < w) { ss[tid] += ss[tid + w]; sq[tid] += sq[tid + w]; }
    __syncthreads();
  }
  if (tid == 0) {
    float mu = ss[0] * kInvCnt;
    float var = sq[0] * kInvCnt - mu * mu;
    var = var < 0.f ? 0.f : var;
    float sc = gam[o] * rsqrtf(var + kEps);
    bn[o] = sc;
    bn[DC + o] = bet[o] - mu * sc;
  }
}

// ---------------------------------------------------------------------------
__global__ void k_final(const float* __restrict__ ymax, const float* __restrict__ ymin,
                        const float* __restrict__ bn2, float* __restrict__ out) {
  __shared__ float tmax[32][33], tmin[32][33];
  int ot = blockIdx.x, pt = blockIdx.y, b = blockIdx.z;
  int tx = threadIdx.x, ty = threadIdx.y;  // 32 x 8
#pragma unroll
  for (int k = 0; k < 4; ++k) {
    int pr = ty + k * 8;
    size_t base = ((size_t)(b * DP) + pt * 32 + pr) * DC + ot * 32 + tx;
    tmax[pr][tx] = ymax[base];
    tmin[pr][tx] = ymin[base];
  }
  __syncthreads();
#pragma unroll
  for (int k = 0; k < 4; ++k) {
    int oc = ty + k * 8;
    int o = ot * 32 + oc;
    float sc = bn2[o], sh = bn2[DC + o];
    float m = (sc >= 0.f) ? tmax[tx][oc] : tmin[tx][oc];
    float v = fmaf(sc, m, sh);
    v = v > 0.f ? v : 0.f;
    out[((size_t)(b * DC) + o) * DP + pt * 32 + tx] = v;
  }
}

// ---------------------------------------------------------------------------
extern "C" void kernel_launch(void* const* d_in, const int* in_sizes, int n_in,
                              void* d_out, int out_size, void* d_ws, size_t ws_size,
                              hipStream_t stream) {
  const float* xyz   = (const float*)d_in[0];
  const float* feats = (const float*)d_in[1];
  const float* rot   = (const float*)d_in[2];
  const float* W1    = (const float*)d_in[3];
  const float* g1    = (const float*)d_in[4];
  const float* b1    = (const float*)d_in[5];
  const float* W2    = (const float*)d_in[6];
  const float* g2    = (const float*)d_in[7];
  const float* b2    = (const float*)d_in[8];
  float* out = (float*)d_out;

  float* ws = (float*)d_ws;
  uint*   ftb_u  = (uint*)(ws + OF_FEATST);
  uint4*  ftb    = (uint4*)(ws + OF_FEATST);
  ushort* W1b    = (ushort*)(ws + OF_W1B);
  ushort* W2b    = (ushort*)(ws + OF_W2B);
  int*    idxp   = (int*)(ws + OF_IDX);
  float*  gxp    = ws + OF_GX;
  float2* partp  = (float2*)(ws + OF_PART);
  float*  ymaxp  = ws + OF_YMAX;
  float*  yminp  = ws + OF_YMIN;
  float*  bn1p   = ws + OF_BN1;
  float*  bn2p   = ws + OF_BN2;
  float*  cntzp  = ws + OF_CNTZ;
  float*  gwzp   = ws + OF_GWZ;
  float*  gg64p  = ws + OF_GG64;
  float2* yprtp  = (float2*)(ws + OF_YPRT);

  k_prep<<<4640, 256, 0, stream>>>(feats, ftb_u, W1, W1b, W2, W2b,
                                   xyz, rot, idxp, gxp);

  // ---- bn1 stats via point-factored algebra (Y-GEMM over unique points) ----
  k_count<<<64, 256, 0, stream>>>(idxp, gxp, cntzp, gwzp, gg64p);
  k_ygemm<<<64, 256, 0, stream>>>(ftb, W1b, W1, cntzp, gwzp, yprtp);
  k_bn1f<<<1, 256, 0, stream>>>(yprtp, gg64p, W1, g1, b1, bn1p);

  // ---- fused GEMM1+bn1+relu+GEMM2 + y2 stats/max/min ----
  k_gemm_full<<<NG, 512, 0, stream>>>(ftb, W1b, W2b, idxp, gxp, bn1p, partp,
                                      ymaxp, yminp);
  k_reduce_bn<<<DC, 256, 0, stream>>>((const float*)partp, g2, b2, bn2p);
  k_final<<<dim3(DC / 32, DP / 32, DB), dim3(32, 8), 0, stream>>>(ymaxp, yminp, bn2p, out);
}

// Round 15
// 181.907 us; speedup vs baseline: 1.0106x; 1.0106x over previous
//
#include <hip/hip_runtime.h>
#include <hip/hip_bf16.h>

#define DB 8
#define DN 1024
#define DP 1024
#define DC 256
#define DNS 32
#define DBP (DB * DP)
#define K1 288   // padded GEMM1 K (256 feats + 3 gx + 29 zeros)
#define K2 256
#define XS 296   // x_lds row stride in bf16 elems (592 B; 148 dwords == 20 mod 32)
#define YS 258   // epilogue y-tile row stride in bf16 (129 dwords == 1 mod 32)
#define ROWS 128 // 4 bp per block
#define NG (DBP / 4)
#define NK1 (K1 / 32)  // 9
#define NK2 (K2 / 32)  // 8

constexpr float kRadius = 0.05f;
constexpr float kR2 = kRadius * kRadius;
constexpr float kHmin = -0.02f;
constexpr float kHmax = 0.04f;
constexpr float kEps = 1e-5f;
constexpr float kInvCnt = 1.0f / (float)(DB * DP * DNS);

typedef __bf16 bf16x8 __attribute__((ext_vector_type(8)));
typedef float f32x4 __attribute__((ext_vector_type(4)));
static_assert(sizeof(bf16x8) == 16, "bf16x8 must be 16B");

// ---- workspace layout (in floats) ----
constexpr size_t OF_FEATST = 0;                                   // B*N*C bf16
constexpr size_t OF_W1B  = OF_FEATST + (size_t)DB * DN * DC / 2;  // DC*K1 bf16
constexpr size_t OF_W2B  = OF_W1B + (size_t)DC * K1 / 2;          // DC*K2 bf16
constexpr size_t OF_IDX  = OF_W2B + (size_t)DC * K2 / 2;          // BP*NS int32
constexpr size_t OF_GX   = OF_IDX + (size_t)DBP * DNS;            // BP*NS*3
constexpr size_t OF_PART = OF_GX + (size_t)DBP * DNS * 3;         // NG*C*2
constexpr size_t OF_YMAX = OF_PART + (size_t)DBP * DC * 2;        // BP*C
constexpr size_t OF_YMIN = OF_YMAX + (size_t)DBP * DC;            // BP*C
constexpr size_t OF_BN1  = OF_YMIN + (size_t)DBP * DC;            // 512
constexpr size_t OF_BN2  = OF_BN1 + 512;                          // 512
// ---- point-factored stats scratch ----
constexpr size_t OF_CNTZ = OF_BN2 + 512;                          // 64*DN
constexpr size_t OF_GWZ  = OF_CNTZ + (size_t)64 * DN;             // 64*3*DN
constexpr size_t OF_GG64 = OF_GWZ + (size_t)64 * 3 * DN;          // 64*16
constexpr size_t OF_YPRT = OF_GG64 + 1024;                        // 64*DC*2

__device__ inline ushort f2b(float x) {
  union { __hip_bfloat16 h; ushort u; } c;
  c.h = __float2bfloat16(x);
  return c.u;
}
__device__ inline float b2f(ushort u) {
  union { uint u; float f; } c;
  c.u = (uint)u << 16;
  return c.f;
}

// ---------------------------------------------------------------------------
// fused pre-pass: [0,2048) transpose feats; [2048,2336) W1 prep; [2336,2592)
// W2 prep; [2592,4640) cylinder query (4 bp per block, one per wave).
__global__ __launch_bounds__(256)
void k_prep(const float* __restrict__ f, uint* __restrict__ ftb,
            const float* __restrict__ W1, ushort* __restrict__ W1b,
            const float* __restrict__ W2, ushort* __restrict__ W2b,
            const float* __restrict__ xyz, const float* __restrict__ rot,
            int* __restrict__ idxp, float* __restrict__ gxp) {
  __shared__ float t[32][33];
  __shared__ int sidx[4][DNS];
  __shared__ float srot[4][9], sc[4][3];
  int blk = blockIdx.x;
  int tid = threadIdx.x;
  if (blk < 2048) {
    int ct = blk & 7, nt = (blk >> 3) & 31, b = blk >> 8;
    int tx = tid & 31, ty = tid >> 5;
#pragma unroll
    for (int k = 0; k < 4; ++k) {
      int c = ct * 32 + ty + k * 8;
      t[ty + k * 8][tx] = f[((size_t)b * DC + c) * DN + nt * 32 + tx];
    }
    __syncthreads();
    uint* dst = ftb + (size_t)b * DN * (DC / 2);
#pragma unroll
    for (int it = 0; it < 2; ++it) {
      int idx = it * 256 + tid;
      int nl = idx >> 4, cp = idx & 15;
      uint v = (uint)f2b(t[2 * cp][nl]) | ((uint)f2b(t[2 * cp + 1][nl]) << 16);
      dst[(size_t)(nt * 32 + nl) * (DC / 2) + ct * 16 + cp] = v;
    }
  } else if (blk < 2336) {
    int gid = (blk - 2048) * 256 + tid;
    if (gid < DC * K1) {
      int o = gid / K1, kp = gid - o * K1;
      float v = 0.f;
      if (kp < 256) v = W1[o * 259 + 3 + kp];
      else if (kp < 259) v = W1[o * 259 + (kp - 256)];
      W1b[gid] = f2b(v);
    }
  } else if (blk < 2592) {
    int gid = (blk - 2336) * 256 + tid;
    if (gid < DC * K2) W2b[gid] = f2b(W2[gid]);
  } else {
    int wv = tid >> 6;
    int lane = tid & 63;
    int bp = (blk - 2592) * 4 + wv;
    int b = bp >> 10;
    if (lane < DNS) sidx[wv][lane] = 0;
    if (lane < 9) srot[wv][lane] = rot[(size_t)bp * 9 + lane];
    if (lane < 3) sc[wv][lane] = xyz[(size_t)bp * 3 + lane];
    float r00 = srot[wv][0], r01 = srot[wv][1], r02 = srot[wv][2];
    float r10 = srot[wv][3], r11 = srot[wv][4], r12 = srot[wv][5];
    float r20 = srot[wv][6], r21 = srot[wv][7], r22 = srot[wv][8];
    float cx = sc[wv][0], cy = sc[wv][1], cz = sc[wv][2];
    const float* xb = xyz + (size_t)b * DN * 3;
    int cnt = 0;
    for (int ch = 0; ch < DN / 64 && cnt < DNS; ++ch) {
      int n = ch * 64 + lane;
      float dx = xb[n * 3 + 0] - cx, dy = xb[n * 3 + 1] - cy, dz = xb[n * 3 + 2] - cz;
      float lx = dx * r00 + dy * r10 + dz * r20;
      float ly = dx * r01 + dy * r11 + dz * r21;
      float lz = dx * r02 + dy * r12 + dz * r22;
      bool m = (ly * ly + lz * lz < kR2) && (lx > kHmin) && (lx < kHmax);
      unsigned long long bal = __ballot(m);
      int rank = cnt + __popcll(bal & ((1ull << lane) - 1ull));
      if (m && rank < DNS) sidx[wv][rank] = n;
      cnt += __popcll(bal);
    }
    if (lane < DNS) {
      int j = sidx[wv][lane];
      idxp[(size_t)bp * DNS + lane] = j;
      float gx = (xb[j * 3 + 0] - cx) / kRadius;
      float gy = (xb[j * 3 + 1] - cy) / kRadius;
      float gz = (xb[j * 3 + 2] - cz) / kRadius;
      float* gp = gxp + ((size_t)bp * DNS + lane) * 3;
      gp[0] = gx * r00 + gy * r10 + gz * r20;
      gp[1] = gx * r01 + gy * r11 + gz * r21;
      gp[2] = gx * r02 + gy * r12 + gz * r22;
    }
  }
}

// ---------------------------------------------------------------------------
// per-point counts + weighted gx sums via LDS histogram, plain-stored into
// per-block slices. 64 blocks x 256. gg64[blk*16+v]: v=0..5 2nd moments, 6..8 sums.
__global__ __launch_bounds__(256)
void k_count(const int* __restrict__ idxp, const float* __restrict__ gxp,
             float* __restrict__ cntz, float* __restrict__ gwz,
             float* __restrict__ gg64) {
  __shared__ float h0[DN], h1[DN], h2[DN], h3[DN];
  int t = threadIdx.x;
  int blk = blockIdx.x;
  int b = blk >> 3, s = blk & 7;
  for (int i = t; i < DN; i += 256) {
    h0[i] = 0.f; h1[i] = 0.f; h2[i] = 0.f; h3[i] = 0.f;
  }
  __syncthreads();
  float p[9] = {0.f, 0.f, 0.f, 0.f, 0.f, 0.f, 0.f, 0.f, 0.f};
#pragma unroll
  for (int r = 0; r < 16; ++r) {
    int sid = blk * 4096 + r * 256 + t;
    int j = idxp[sid];
    const float* g = gxp + (size_t)sid * 3;
    float g0 = g[0], g1 = g[1], g2 = g[2];
    atomicAdd(&h0[j], 1.f);
    atomicAdd(&h1[j], g0);
    atomicAdd(&h2[j], g1);
    atomicAdd(&h3[j], g2);
    p[0] += g0 * g0; p[1] += g0 * g1; p[2] += g0 * g2;
    p[3] += g1 * g1; p[4] += g1 * g2; p[5] += g2 * g2;
    p[6] += g0; p[7] += g1; p[8] += g2;
  }
  __syncthreads();
  for (int i = t; i < DN; i += 256) {
    cntz[((size_t)b * 8 + s) * DN + i] = h0[i];
    gwz[(((size_t)b * 8 + s) * 3 + 0) * DN + i] = h1[i];
    gwz[(((size_t)b * 8 + s) * 3 + 1) * DN + i] = h2[i];
    gwz[(((size_t)b * 8 + s) * 3 + 2) * DN + i] = h3[i];
  }
  __shared__ float sgg[4][9];
#pragma unroll
  for (int v = 0; v < 9; ++v) {
    float sv = p[v];
#pragma unroll
    for (int m = 1; m < 64; m <<= 1) sv += __shfl_xor(sv, m, 64);
    if ((t & 63) == 0) sgg[t >> 6][v] = sv;
  }
  __syncthreads();
  if (t < 9) gg64[blk * 16 + t] = sgg[0][t] + sgg[1][t] + sgg[2][t] + sgg[3][t];
}

// ---------------------------------------------------------------------------
// Yf = W1_feat x feats over unique points (K=256, no gather), fused weighted
// stats. 64 blocks x 256 thr.
__global__ __launch_bounds__(256)
void k_ygemm(const uint4* __restrict__ ftb, const ushort* __restrict__ W1b,
             const float* __restrict__ W1, const float* __restrict__ cntz,
             const float* __restrict__ gwz, float2* __restrict__ ypart) {
  __shared__ ushort x_lds[ROWS * XS];
  __shared__ float c_lds[ROWS];
  __shared__ float g_lds[3][ROWS];
  __shared__ float wg_lds[DC][3];

  const int nb = blockIdx.x;       // 0..63
  const int b = nb >> 3;
  const int n0 = (nb & 7) * ROWS;
  const int tid = threadIdx.x;
  const int lane = tid & 63;
  const int wv = tid >> 6;
  const int l15 = lane & 15;
  const int l4 = lane >> 4;

  {
    const uint4* src = ftb + ((size_t)b * DN + n0) * (DC / 8);
    for (int idx = tid; idx < ROWS * 32; idx += 256) {
      int rrow = idx >> 5, col = idx & 31;
      ((uint4*)(x_lds + (size_t)rrow * XS))[col] = src[rrow * 32 + col];
    }
  }
  if (tid < ROWS) {
    float c = 0.f, g0 = 0.f, g1 = 0.f, g2 = 0.f;
#pragma unroll
    for (int s = 0; s < 8; ++s) {
      c += cntz[((size_t)b * 8 + s) * DN + n0 + tid];
      g0 += gwz[(((size_t)b * 8 + s) * 3 + 0) * DN + n0 + tid];
      g1 += gwz[(((size_t)b * 8 + s) * 3 + 1) * DN + n0 + tid];
      g2 += gwz[(((size_t)b * 8 + s) * 3 + 2) * DN + n0 + tid];
    }
    c_lds[tid] = c; g_lds[0][tid] = g0; g_lds[1][tid] = g1; g_lds[2][tid] = g2;
  }
  {
    wg_lds[tid][0] = W1[tid * 259 + 0];
    wg_lds[tid][1] = W1[tid * 259 + 1];
    wg_lds[tid][2] = W1[tid * 259 + 2];
  }
  __syncthreads();

  f32x4 acc[4][8];
#pragma unroll
  for (int t = 0; t < 4; ++t)
#pragma unroll
    for (int st = 0; st < 8; ++st)
#pragma unroll
      for (int r = 0; r < 4; ++r) acc[t][st][r] = 0.f;

  const int o0 = wv * 64;
  const ushort* xbase = x_lds + (size_t)l15 * XS + l4 * 8;
  {
    const ushort* wrow[4];
#pragma unroll
    for (int t = 0; t < 4; ++t)
      wrow[t] = W1b + (size_t)(o0 + t * 16 + l15) * K1 + l4 * 8;
#pragma unroll
    for (int ks = 0; ks < 8; ++ks) {
      bf16x8 bx[8], aw[4];
#pragma unroll
      for (int st = 0; st < 8; ++st)
        bx[st] = *(const bf16x8*)(xbase + (size_t)st * 16 * XS + ks * 32);
#pragma unroll
      for (int t = 0; t < 4; ++t) aw[t] = *(const bf16x8*)(wrow[t] + ks * 32);
#pragma unroll
      for (int st = 0; st < 8; ++st)
#pragma unroll
        for (int t = 0; t < 4; ++t)
          acc[t][st] = __builtin_amdgcn_mfma_f32_16x16x32_bf16(aw[t], bx[st],
                                                               acc[t][st], 0, 0, 0);
    }
  }

  float cn[8], h0[8], h1[8], h2[8];
#pragma unroll
  for (int st = 0; st < 8; ++st) {
    int n = st * 16 + l15;
    cn[st] = c_lds[n]; h0[st] = g_lds[0][n]; h1[st] = g_lds[1][n]; h2[st] = g_lds[2][n];
  }
#pragma unroll
  for (int t = 0; t < 4; ++t) {
#pragma unroll
    for (int r = 0; r < 4; ++r) {
      int o = o0 + t * 16 + l4 * 4 + r;
      float wg0 = wg_lds[o][0], wg1 = wg_lds[o][1], wg2 = wg_lds[o][2];
      float s = 0.f, q = 0.f;
#pragma unroll
      for (int st = 0; st < 8; ++st) {
        float Y = acc[t][st][r];
        float h = wg0 * h0[st] + wg1 * h1[st] + wg2 * h2[st];
        s = fmaf(cn[st], Y, s);
        q += cn[st] * Y * Y + 2.f * Y * h;
      }
#pragma unroll
      for (int m = 1; m < 16; m <<= 1) {
        s += __shfl_xor(s, m, 64);
        q += __shfl_xor(q, m, 64);
      }
      if (l15 == 0) ypart[(size_t)nb * DC + o] = make_float2(s, q);
    }
  }
}

// ---------------------------------------------------------------------------
__global__ __launch_bounds__(256)
void k_bn1f(const float2* __restrict__ ypart, const float* __restrict__ gg64,
            const float* __restrict__ W1, const float* __restrict__ gam,
            const float* __restrict__ bet, float* __restrict__ bn) {
  __shared__ float ggs[9];
  int t = threadIdx.x;
  if (t < 9) {
    float s = 0.f;
    for (int blk = 0; blk < 64; ++blk) s += gg64[blk * 16 + t];
    ggs[t] = s;
  }
  __syncthreads();
  float s = 0.f, q = 0.f;
  for (int nb = 0; nb < 64; ++nb) {
    float2 v = ypart[(size_t)nb * DC + t];
    s += v.x; q += v.y;
  }
  float wg0 = W1[t * 259 + 0], wg1 = W1[t * 259 + 1], wg2 = W1[t * 259 + 2];
  s += wg0 * ggs[6] + wg1 * ggs[7] + wg2 * ggs[8];
  q += wg0 * wg0 * ggs[0] + 2.f * wg0 * wg1 * ggs[1] + 2.f * wg0 * wg2 * ggs[2] +
       wg1 * wg1 * ggs[3] + 2.f * wg1 * wg2 * ggs[4] + wg2 * wg2 * ggs[5];
  float mu = s * kInvCnt;
  float var = q * kInvCnt - mu * mu;
  var = var < 0.f ? 0.f : var;
  float sc = gam[t] * rsqrtf(var + kEps);
  bn[t] = sc;
  bn[DC + t] = bet[t] - mu * sc;
}

// ---------------------------------------------------------------------------
// MFMA GEMM over 4 bp per block, 16x16x32 bf16 — 512 threads / 8 waves.
// Wave w owns 2 o-tiles (o0 = w*32), all 8 s-tiles (round-13 best shape),
// with 2-deep A prefetch: A-from-L2 latency was the binding pipe (r13 vs r14).
// D layout: col = lane&15 (=s), row = (lane>>4)*4 + reg (=o).
__global__ __launch_bounds__(512, 4)
void k_gemm_full(const uint4* __restrict__ ftb, const ushort* __restrict__ W1b,
                 const ushort* __restrict__ W2b, const int* __restrict__ idxp,
                 const float* __restrict__ gxp, const float* __restrict__ bn1,
                 float2* __restrict__ part, float* __restrict__ ymax,
                 float* __restrict__ ymin) {
  __shared__ ushort x_lds[ROWS * XS];   // 75776 B; also holds 128x258 y tile
  __shared__ float bn_lds[2 * DC];

  const int grp = blockIdx.x;           // 0..NG-1
  const int bp0 = grp * 4;
  const int b = bp0 >> 10;
  const int tid = threadIdx.x;          // 0..511
  const int lane = tid & 63;
  const int wv = tid >> 6;              // 0..7
  const int l15 = lane & 15;
  const int l4 = lane >> 4;

  bn_lds[tid] = bn1[tid];               // 512 threads == 2*DC

  // ---- gather feats: 8 threads/row, 128-B coalesced segments, 2 passes ----
  {
    int q = tid & 7;
#pragma unroll
    for (int rep = 0; rep < 2; ++rep) {
      int s = (tid >> 3) + rep * 64;
      int j = idxp[(size_t)bp0 * DNS + s];
      const uint4* src = ftb + (size_t)(b * DN + j) * (DC / 8);
      uint4* dst = (uint4*)(x_lds + (size_t)s * XS);
#pragma unroll
      for (int k = 0; k < 4; ++k) dst[q + 8 * k] = src[q + 8 * k];
    }
  }
  // ---- gx channels at k=256..258, zeros to 287 ----
  if (tid < ROWS) {
    const float* g = gxp + ((size_t)bp0 * DNS + tid) * 3;
    uint a0 = (uint)f2b(g[0]) | ((uint)f2b(g[1]) << 16);
    uint a1 = (uint)f2b(g[2]);
    uint4* drow = (uint4*)(x_lds + (size_t)tid * XS + 256);
    drow[0] = make_uint4(a0, a1, 0u, 0u);
    drow[1] = make_uint4(0u, 0u, 0u, 0u);
    drow[2] = make_uint4(0u, 0u, 0u, 0u);
    drow[3] = make_uint4(0u, 0u, 0u, 0u);
  }
  __syncthreads();

  f32x4 acc[2][8];
#pragma unroll
  for (int t = 0; t < 2; ++t)
#pragma unroll
    for (int st = 0; st < 8; ++st)
#pragma unroll
      for (int r = 0; r < 4; ++r) acc[t][st][r] = 0.f;

  const int o0 = wv * 32;
  const ushort* xbase = x_lds + (size_t)l15 * XS + l4 * 8;

  // ---- GEMM1: K = 288, 9 K-steps of 32; A prefetched TWO steps ahead ----
  {
    const ushort* wrow[2];
#pragma unroll
    for (int t = 0; t < 2; ++t)
      wrow[t] = W1b + (size_t)(o0 + t * 16 + l15) * K1 + l4 * 8;
    bf16x8 aw[2], a1[2];
#pragma unroll
    for (int t = 0; t < 2; ++t) aw[t] = *(const bf16x8*)(wrow[t]);
#pragma unroll
    for (int t = 0; t < 2; ++t) a1[t] = *(const bf16x8*)(wrow[t] + 32);
#pragma unroll
    for (int ks = 0; ks < NK1; ++ks) {
      bf16x8 bx[8];
#pragma unroll
      for (int st = 0; st < 8; ++st)
        bx[st] = *(const bf16x8*)(xbase + (size_t)st * 16 * XS + ks * 32);
      bf16x8 a2[2];
      if (ks + 2 < NK1) {
#pragma unroll
        for (int t = 0; t < 2; ++t)
          a2[t] = *(const bf16x8*)(wrow[t] + (ks + 2) * 32);
      }
      __builtin_amdgcn_s_setprio(1);
#pragma unroll
      for (int st = 0; st < 8; ++st)
#pragma unroll
        for (int t = 0; t < 2; ++t)
          acc[t][st] = __builtin_amdgcn_mfma_f32_16x16x32_bf16(aw[t], bx[st],
                                                               acc[t][st], 0, 0, 0);
      __builtin_amdgcn_s_setprio(0);
      if (ks + 1 < NK1) {
#pragma unroll
        for (int t = 0; t < 2; ++t) aw[t] = a1[t];
      }
      if (ks + 2 < NK1) {
#pragma unroll
        for (int t = 0; t < 2; ++t) a1[t] = a2[t];
      }
    }
  }

  // ---- bn1 + relu -> x2 (bf16) back into x_lds[s][o] (stride XS) ----
  __syncthreads();  // all GEMM1 LDS reads complete before overwrite
#pragma unroll
  for (int t = 0; t < 2; ++t) {
    int ob = o0 + t * 16 + l4 * 4;
    float sc0 = bn_lds[ob + 0], sh0 = bn_lds[DC + ob + 0];
    float sc1 = bn_lds[ob + 1], sh1 = bn_lds[DC + ob + 1];
    float sc2 = bn_lds[ob + 2], sh2 = bn_lds[DC + ob + 2];
    float sc3 = bn_lds[ob + 3], sh3 = bn_lds[DC + ob + 3];
#pragma unroll
    for (int st = 0; st < 8; ++st) {
      float v0 = fmaxf(fmaf(acc[t][st][0], sc0, sh0), 0.f);
      float v1 = fmaxf(fmaf(acc[t][st][1], sc1, sh1), 0.f);
      float v2 = fmaxf(fmaf(acc[t][st][2], sc2, sh2), 0.f);
      float v3 = fmaxf(fmaf(acc[t][st][3], sc3, sh3), 0.f);
      uint2 pk = make_uint2((uint)f2b(v0) | ((uint)f2b(v1) << 16),
                            (uint)f2b(v2) | ((uint)f2b(v3) << 16));
      int s = st * 16 + l15;
      *(uint2*)(x_lds + (size_t)s * XS + ob) = pk;
      acc[t][st][0] = 0.f; acc[t][st][1] = 0.f;
      acc[t][st][2] = 0.f; acc[t][st][3] = 0.f;
    }
  }
  __syncthreads();

  // ---- GEMM2: K = 256, 8 K-steps; A prefetched TWO steps ahead ----
  {
    const ushort* wrow[2];
#pragma unroll
    for (int t = 0; t < 2; ++t)
      wrow[t] = W2b + (size_t)(o0 + t * 16 + l15) * K2 + l4 * 8;
    bf16x8 aw[2], a1[2];
#pragma unroll
    for (int t = 0; t < 2; ++t) aw[t] = *(const bf16x8*)(wrow[t]);
#pragma unroll
    for (int t = 0; t < 2; ++t) a1[t] = *(const bf16x8*)(wrow[t] + 32);
#pragma unroll
    for (int ks = 0; ks < NK2; ++ks) {
      bf16x8 bx[8];
#pragma unroll
      for (int st = 0; st < 8; ++st)
        bx[st] = *(const bf16x8*)(xbase + (size_t)st * 16 * XS + ks * 32);
      bf16x8 a2[2];
      if (ks + 2 < NK2) {
#pragma unroll
        for (int t = 0; t < 2; ++t)
          a2[t] = *(const bf16x8*)(wrow[t] + (ks + 2) * 32);
      }
      __builtin_amdgcn_s_setprio(1);
#pragma unroll
      for (int st = 0; st < 8; ++st)
#pragma unroll
        for (int t = 0; t < 2; ++t)
          acc[t][st] = __builtin_amdgcn_mfma_f32_16x16x32_bf16(aw[t], bx[st],
                                                               acc[t][st], 0, 0, 0);
      __builtin_amdgcn_s_setprio(0);
      if (ks + 1 < NK2) {
#pragma unroll
        for (int t = 0; t < 2; ++t) aw[t] = a1[t];
      }
      if (ks + 2 < NK2) {
#pragma unroll
        for (int t = 0; t < 2; ++t) a1[t] = a2[t];
      }
    }
  }

  // ---- y2 -> bf16 [s][o] tile, then per-o column stats + per-bp max/min ----
  __syncthreads();
#pragma unroll
  for (int t = 0; t < 2; ++t) {
    int ob = o0 + t * 16 + l4 * 4;
#pragma unroll
    for (int st = 0; st < 8; ++st) {
      uint2 pk = make_uint2(
          (uint)f2b(acc[t][st][0]) | ((uint)f2b(acc[t][st][1]) << 16),
          (uint)f2b(acc[t][st][2]) | ((uint)f2b(acc[t][st][3]) << 16));
      int s = st * 16 + l15;
      *(uint2*)(x_lds + (size_t)s * YS + ob) = pk;
    }
  }
  __syncthreads();
  {
    // partial-sum scratch in the free tail of x_lds (bytes 66048..70144)
    float* redp = (float*)(x_lds + (size_t)ROWS * YS);
    int o = tid & 255, half = tid >> 8;   // half: rows [half*64, half*64+64)
    const ushort* col = x_lds + o;
    float s = 0.f, q = 0.f;
#pragma unroll
    for (int p2 = 0; p2 < 2; ++p2) {
      int p = half * 2 + p2;              // bp index 0..3
      float mx = -3.4e38f, mn = 3.4e38f;
#pragma unroll 8
      for (int i = 0; i < DNS; ++i) {
        float v = b2f(col[(size_t)(p * DNS + i) * YS]);
        s += v; q += v * v;
        mx = fmaxf(mx, v); mn = fminf(mn, v);
      }
      ymax[(size_t)(bp0 + p) * DC + o] = mx;
      ymin[(size_t)(bp0 + p) * DC + o] = mn;
    }
    redp[half * 256 + o] = s;
    redp[512 + half * 256 + o] = q;
    __syncthreads();
    if (tid < 256) {
      float ss = redp[tid] + redp[256 + tid];
      float qq = redp[512 + tid] + redp[768 + tid];
      part[(size_t)grp * DC + tid] = make_float2(ss, qq);
    }
  }
}

// ---------------------------------------------------------------------------
__global__ void k_reduce_bn(const float* __restrict__ part, const float* __restrict__ gam,
                            const float* __restrict__ bet, float* __restrict__ bn) {
  int o = blockIdx.x, tid = threadIdx.x;
  __shared__ float ss[256], sq[256];
  float s = 0.f, q = 0.f;
  const float2* pp = (const float2*)part;
  for (int g = tid; g < NG; g += 256) {
    float2 v = pp[(size_t)g * DC + o];
    s += v.x; q += v.y;
  }
  ss[tid] = s; sq[tid] = q;
  __syncthreads();
  for (int w = 128; w > 0; w >>= 1) {
    if (tid < w) { ss[tid] += ss[tid + w]; sq[tid] += sq[tid + w]; }
    __syncthreads();
  }
  if (tid == 0) {
    float mu = ss[0] * kInvCnt;
    float var = sq[0] * kInvCnt - mu * mu;
    var = var < 0.f ? 0.f : var;
    float sc = gam[o] * rsqrtf(var + kEps);
    bn[o] = sc;
    bn[DC + o] = bet[o] - mu * sc;
  }
}

// ---------------------------------------------------------------------------
__global__ void k_final(const float* __restrict__ ymax, const float* __restrict__ ymin,
                        const float* __restrict__ bn2, float* __restrict__ out) {
  __shared__ float tmax[32][33], tmin[32][33];
  int ot = blockIdx.x, pt = blockIdx.y, b = blockIdx.z;
  int tx = threadIdx.x, ty = threadIdx.y;  // 32 x 8
#pragma unroll
  for (int k = 0; k < 4; ++k) {
    int pr = ty + k * 8;
    size_t base = ((size_t)(b * DP) + pt * 32 + pr) * DC + ot * 32 + tx;
    tmax[pr][tx] = ymax[base];
    tmin[pr][tx] = ymin[base];
  }
  __syncthreads();
#pragma unroll
  for (int k = 0; k < 4; ++k) {
    int oc = ty + k * 8;
    int o = ot * 32 + oc;
    float sc = bn2[o], sh = bn2[DC + o];
    float m = (sc >= 0.f) ? tmax[tx][oc] : tmin[tx][oc];
    float v = fmaf(sc, m, sh);
    v = v > 0.f ? v : 0.f;
    out[((size_t)(b * DC) + o) * DP + pt * 32 + tx] = v;
  }
}

// ---------------------------------------------------------------------------
extern "C" void kernel_launch(void* const* d_in, const int* in_sizes, int n_in,
                              void* d_out, int out_size, void* d_ws, size_t ws_size,
                              hipStream_t stream) {
  const float* xyz   = (const float*)d_in[0];
  const float* feats = (const float*)d_in[1];
  const float* rot   = (const float*)d_in[2];
  const float* W1    = (const float*)d_in[3];
  const float* g1    = (const float*)d_in[4];
  const float* b1    = (const float*)d_in[5];
  const float* W2    = (const float*)d_in[6];
  const float* g2    = (const float*)d_in[7];
  const float* b2    = (const float*)d_in[8];
  float* out = (float*)d_out;

  float* ws = (float*)d_ws;
  uint*   ftb_u  = (uint*)(ws + OF_FEATST);
  uint4*  ftb    = (uint4*)(ws + OF_FEATST);
  ushort* W1b    = (ushort*)(ws + OF_W1B);
  ushort* W2b    = (ushort*)(ws + OF_W2B);
  int*    idxp   = (int*)(ws + OF_IDX);
  float*  gxp    = ws + OF_GX;
  float2* partp  = (float2*)(ws + OF_PART);
  float*  ymaxp  = ws + OF_YMAX;
  float*  yminp  = ws + OF_YMIN;
  float*  bn1p   = ws + OF_BN1;
  float*  bn2p   = ws + OF_BN2;
  float*  cntzp  = ws + OF_CNTZ;
  float*  gwzp   = ws + OF_GWZ;
  float*  gg64p  = ws + OF_GG64;
  float2* yprtp  = (float2*)(ws + OF_YPRT);

  k_prep<<<4640, 256, 0, stream>>>(feats, ftb_u, W1, W1b, W2, W2b,
                                   xyz, rot, idxp, gxp);

  // ---- bn1 stats via point-factored algebra (Y-GEMM over unique points) ----
  k_count<<<64, 256, 0, stream>>>(idxp, gxp, cntzp, gwzp, gg64p);
  k_ygemm<<<64, 256, 0, stream>>>(ftb, W1b, W1, cntzp, gwzp, yprtp);
  k_bn1f<<<1, 256, 0, stream>>>(yprtp, gg64p, W1, g1, b1, bn1p);

  // ---- fused GEMM1+bn1+relu+GEMM2 + y2 stats/max/min ----
  k_gemm_full<<<NG, 512, 0, stream>>>(ftb, W1b, W2b, idxp, gxp, bn1p, partp,
                                      ymaxp, yminp);
  k_reduce_bn<<<DC, 256, 0, stream>>>((const float*)partp, g2, b2, bn2p);
  k_final<<<dim3(DC / 32, DP / 32, DB), dim3(32, 8), 0, stream>>>(ymaxp, yminp, bn2p, out);
}

// Round 16
// 155.036 us; speedup vs baseline: 1.1858x; 1.1733x over previous
//
#include <hip/hip_runtime.h>
#include <hip/hip_bf16.h>

#define DB 8
#define DN 1024
#define DP 1024
#define DC 256
#define DNS 32
#define DBP (DB * DP)
#define K1 288   // padded GEMM1 K (256 feats + 3 gx + 29 zeros)
#define K2 256
#define XS 296   // x_lds row stride in bf16 elems (592 B; 148 dwords == 20 mod 32)
#define YS 258   // epilogue y-tile row stride in bf16 (129 dwords == 1 mod 32)
#define ROWS 128 // 4 bp per block
#define NG (DBP / 4)
#define NK1 (K1 / 32)  // 9
#define NK2 (K2 / 32)  // 8

constexpr float kRadius = 0.05f;
constexpr float kR2 = kRadius * kRadius;
constexpr float kHmin = -0.02f;
constexpr float kHmax = 0.04f;
constexpr float kEps = 1e-5f;
constexpr float kInvCnt = 1.0f / (float)(DB * DP * DNS);

typedef __bf16 bf16x8 __attribute__((ext_vector_type(8)));
typedef float f32x4 __attribute__((ext_vector_type(4)));
static_assert(sizeof(bf16x8) == 16, "bf16x8 must be 16B");

// ---- workspace layout (in floats) ----
constexpr size_t OF_FEATST = 0;                                   // B*N*C bf16
constexpr size_t OF_W1B  = OF_FEATST + (size_t)DB * DN * DC / 2;  // DC*K1 bf16
constexpr size_t OF_W2B  = OF_W1B + (size_t)DC * K1 / 2;          // DC*K2 bf16
constexpr size_t OF_IDX  = OF_W2B + (size_t)DC * K2 / 2;          // BP*NS int32
constexpr size_t OF_GX   = OF_IDX + (size_t)DBP * DNS;            // BP*NS*3
constexpr size_t OF_PART = OF_GX + (size_t)DBP * DNS * 3;         // NG*C*2
constexpr size_t OF_YMAX = OF_PART + (size_t)DBP * DC * 2;        // BP*C
constexpr size_t OF_YMIN = OF_YMAX + (size_t)DBP * DC;            // BP*C
constexpr size_t OF_BN1  = OF_YMIN + (size_t)DBP * DC;            // 512
constexpr size_t OF_BN2  = OF_BN1 + 512;                          // 512
// ---- point-factored stats scratch ----
constexpr size_t OF_CNTZ = OF_BN2 + 512;                          // 64*DN
constexpr size_t OF_GWZ  = OF_CNTZ + (size_t)64 * DN;             // 64*3*DN
constexpr size_t OF_GG64 = OF_GWZ + (size_t)64 * 3 * DN;          // 64*16
constexpr size_t OF_YPRT = OF_GG64 + 1024;                        // 64*DC*2

__device__ inline ushort f2b(float x) {
  union { __hip_bfloat16 h; ushort u; } c;
  c.h = __float2bfloat16(x);
  return c.u;
}
__device__ inline float b2f(ushort u) {
  union { uint u; float f; } c;
  c.u = (uint)u << 16;
  return c.f;
}

// ---------------------------------------------------------------------------
// fused pre-pass: [0,2048) transpose feats; [2048,2336) W1 prep; [2336,2592)
// W2 prep; [2592,4640) cylinder query (4 bp per block, one per wave).
__global__ __launch_bounds__(256)
void k_prep(const float* __restrict__ f, uint* __restrict__ ftb,
            const float* __restrict__ W1, ushort* __restrict__ W1b,
            const float* __restrict__ W2, ushort* __restrict__ W2b,
            const float* __restrict__ xyz, const float* __restrict__ rot,
            int* __restrict__ idxp, float* __restrict__ gxp) {
  __shared__ float t[32][33];
  __shared__ int sidx[4][DNS];
  __shared__ float srot[4][9], sc[4][3];
  int blk = blockIdx.x;
  int tid = threadIdx.x;
  if (blk < 2048) {
    int ct = blk & 7, nt = (blk >> 3) & 31, b = blk >> 8;
    int tx = tid & 31, ty = tid >> 5;
#pragma unroll
    for (int k = 0; k < 4; ++k) {
      int c = ct * 32 + ty + k * 8;
      t[ty + k * 8][tx] = f[((size_t)b * DC + c) * DN + nt * 32 + tx];
    }
    __syncthreads();
    uint* dst = ftb + (size_t)b * DN * (DC / 2);
#pragma unroll
    for (int it = 0; it < 2; ++it) {
      int idx = it * 256 + tid;
      int nl = idx >> 4, cp = idx & 15;
      uint v = (uint)f2b(t[2 * cp][nl]) | ((uint)f2b(t[2 * cp + 1][nl]) << 16);
      dst[(size_t)(nt * 32 + nl) * (DC / 2) + ct * 16 + cp] = v;
    }
  } else if (blk < 2336) {
    int gid = (blk - 2048) * 256 + tid;
    if (gid < DC * K1) {
      int o = gid / K1, kp = gid - o * K1;
      float v = 0.f;
      if (kp < 256) v = W1[o * 259 + 3 + kp];
      else if (kp < 259) v = W1[o * 259 + (kp - 256)];
      W1b[gid] = f2b(v);
    }
  } else if (blk < 2592) {
    int gid = (blk - 2336) * 256 + tid;
    if (gid < DC * K2) W2b[gid] = f2b(W2[gid]);
  } else {
    int wv = tid >> 6;
    int lane = tid & 63;
    int bp = (blk - 2592) * 4 + wv;
    int b = bp >> 10;
    if (lane < DNS) sidx[wv][lane] = 0;
    if (lane < 9) srot[wv][lane] = rot[(size_t)bp * 9 + lane];
    if (lane < 3) sc[wv][lane] = xyz[(size_t)bp * 3 + lane];
    float r00 = srot[wv][0], r01 = srot[wv][1], r02 = srot[wv][2];
    float r10 = srot[wv][3], r11 = srot[wv][4], r12 = srot[wv][5];
    float r20 = srot[wv][6], r21 = srot[wv][7], r22 = srot[wv][8];
    float cx = sc[wv][0], cy = sc[wv][1], cz = sc[wv][2];
    const float* xb = xyz + (size_t)b * DN * 3;
    int cnt = 0;
    for (int ch = 0; ch < DN / 64 && cnt < DNS; ++ch) {
      int n = ch * 64 + lane;
      float dx = xb[n * 3 + 0] - cx, dy = xb[n * 3 + 1] - cy, dz = xb[n * 3 + 2] - cz;
      float lx = dx * r00 + dy * r10 + dz * r20;
      float ly = dx * r01 + dy * r11 + dz * r21;
      float lz = dx * r02 + dy * r12 + dz * r22;
      bool m = (ly * ly + lz * lz < kR2) && (lx > kHmin) && (lx < kHmax);
      unsigned long long bal = __ballot(m);
      int rank = cnt + __popcll(bal & ((1ull << lane) - 1ull));
      if (m && rank < DNS) sidx[wv][rank] = n;
      cnt += __popcll(bal);
    }
    if (lane < DNS) {
      int j = sidx[wv][lane];
      idxp[(size_t)bp * DNS + lane] = j;
      float gx = (xb[j * 3 + 0] - cx) / kRadius;
      float gy = (xb[j * 3 + 1] - cy) / kRadius;
      float gz = (xb[j * 3 + 2] - cz) / kRadius;
      float* gp = gxp + ((size_t)bp * DNS + lane) * 3;
      gp[0] = gx * r00 + gy * r10 + gz * r20;
      gp[1] = gx * r01 + gy * r11 + gz * r21;
      gp[2] = gx * r02 + gy * r12 + gz * r22;
    }
  }
}

// ---------------------------------------------------------------------------
// per-point counts + weighted gx sums via LDS histogram, plain-stored into
// per-block slices. 64 blocks x 256. gg64[blk*16+v]: v=0..5 2nd moments, 6..8 sums.
__global__ __launch_bounds__(256)
void k_count(const int* __restrict__ idxp, const float* __restrict__ gxp,
             float* __restrict__ cntz, float* __restrict__ gwz,
             float* __restrict__ gg64) {
  __shared__ float h0[DN], h1[DN], h2[DN], h3[DN];
  int t = threadIdx.x;
  int blk = blockIdx.x;
  int b = blk >> 3, s = blk & 7;
  for (int i = t; i < DN; i += 256) {
    h0[i] = 0.f; h1[i] = 0.f; h2[i] = 0.f; h3[i] = 0.f;
  }
  __syncthreads();
  float p[9] = {0.f, 0.f, 0.f, 0.f, 0.f, 0.f, 0.f, 0.f, 0.f};
#pragma unroll
  for (int r = 0; r < 16; ++r) {
    int sid = blk * 4096 + r * 256 + t;
    int j = idxp[sid];
    const float* g = gxp + (size_t)sid * 3;
    float g0 = g[0], g1 = g[1], g2 = g[2];
    atomicAdd(&h0[j], 1.f);
    atomicAdd(&h1[j], g0);
    atomicAdd(&h2[j], g1);
    atomicAdd(&h3[j], g2);
    p[0] += g0 * g0; p[1] += g0 * g1; p[2] += g0 * g2;
    p[3] += g1 * g1; p[4] += g1 * g2; p[5] += g2 * g2;
    p[6] += g0; p[7] += g1; p[8] += g2;
  }
  __syncthreads();
  for (int i = t; i < DN; i += 256) {
    cntz[((size_t)b * 8 + s) * DN + i] = h0[i];
    gwz[(((size_t)b * 8 + s) * 3 + 0) * DN + i] = h1[i];
    gwz[(((size_t)b * 8 + s) * 3 + 1) * DN + i] = h2[i];
    gwz[(((size_t)b * 8 + s) * 3 + 2) * DN + i] = h3[i];
  }
  __shared__ float sgg[4][9];
#pragma unroll
  for (int v = 0; v < 9; ++v) {
    float sv = p[v];
#pragma unroll
    for (int m = 1; m < 64; m <<= 1) sv += __shfl_xor(sv, m, 64);
    if ((t & 63) == 0) sgg[t >> 6][v] = sv;
  }
  __syncthreads();
  if (t < 9) gg64[blk * 16 + t] = sgg[0][t] + sgg[1][t] + sgg[2][t] + sgg[3][t];
}

// ---------------------------------------------------------------------------
// Yf = W1_feat x feats over unique points (K=256, no gather), fused weighted
// stats. 64 blocks x 256 thr.
__global__ __launch_bounds__(256)
void k_ygemm(const uint4* __restrict__ ftb, const ushort* __restrict__ W1b,
             const float* __restrict__ W1, const float* __restrict__ cntz,
             const float* __restrict__ gwz, float2* __restrict__ ypart) {
  __shared__ ushort x_lds[ROWS * XS];
  __shared__ float c_lds[ROWS];
  __shared__ float g_lds[3][ROWS];
  __shared__ float wg_lds[DC][3];

  const int nb = blockIdx.x;       // 0..63
  const int b = nb >> 3;
  const int n0 = (nb & 7) * ROWS;
  const int tid = threadIdx.x;
  const int lane = tid & 63;
  const int wv = tid >> 6;
  const int l15 = lane & 15;
  const int l4 = lane >> 4;

  {
    const uint4* src = ftb + ((size_t)b * DN + n0) * (DC / 8);
    for (int idx = tid; idx < ROWS * 32; idx += 256) {
      int rrow = idx >> 5, col = idx & 31;
      ((uint4*)(x_lds + (size_t)rrow * XS))[col] = src[rrow * 32 + col];
    }
  }
  if (tid < ROWS) {
    float c = 0.f, g0 = 0.f, g1 = 0.f, g2 = 0.f;
#pragma unroll
    for (int s = 0; s < 8; ++s) {
      c += cntz[((size_t)b * 8 + s) * DN + n0 + tid];
      g0 += gwz[(((size_t)b * 8 + s) * 3 + 0) * DN + n0 + tid];
      g1 += gwz[(((size_t)b * 8 + s) * 3 + 1) * DN + n0 + tid];
      g2 += gwz[(((size_t)b * 8 + s) * 3 + 2) * DN + n0 + tid];
    }
    c_lds[tid] = c; g_lds[0][tid] = g0; g_lds[1][tid] = g1; g_lds[2][tid] = g2;
  }
  {
    wg_lds[tid][0] = W1[tid * 259 + 0];
    wg_lds[tid][1] = W1[tid * 259 + 1];
    wg_lds[tid][2] = W1[tid * 259 + 2];
  }
  __syncthreads();

  f32x4 acc[4][8];
#pragma unroll
  for (int t = 0; t < 4; ++t)
#pragma unroll
    for (int st = 0; st < 8; ++st)
#pragma unroll
      for (int r = 0; r < 4; ++r) acc[t][st][r] = 0.f;

  const int o0 = wv * 64;
  const ushort* xbase = x_lds + (size_t)l15 * XS + l4 * 8;
  {
    const ushort* wrow[4];
#pragma unroll
    for (int t = 0; t < 4; ++t)
      wrow[t] = W1b + (size_t)(o0 + t * 16 + l15) * K1 + l4 * 8;
#pragma unroll
    for (int ks = 0; ks < 8; ++ks) {
      bf16x8 bx[8], aw[4];
#pragma unroll
      for (int st = 0; st < 8; ++st)
        bx[st] = *(const bf16x8*)(xbase + (size_t)st * 16 * XS + ks * 32);
#pragma unroll
      for (int t = 0; t < 4; ++t) aw[t] = *(const bf16x8*)(wrow[t] + ks * 32);
#pragma unroll
      for (int st = 0; st < 8; ++st)
#pragma unroll
        for (int t = 0; t < 4; ++t)
          acc[t][st] = __builtin_amdgcn_mfma_f32_16x16x32_bf16(aw[t], bx[st],
                                                               acc[t][st], 0, 0, 0);
    }
  }

  float cn[8], h0[8], h1[8], h2[8];
#pragma unroll
  for (int st = 0; st < 8; ++st) {
    int n = st * 16 + l15;
    cn[st] = c_lds[n]; h0[st] = g_lds[0][n]; h1[st] = g_lds[1][n]; h2[st] = g_lds[2][n];
  }
#pragma unroll
  for (int t = 0; t < 4; ++t) {
#pragma unroll
    for (int r = 0; r < 4; ++r) {
      int o = o0 + t * 16 + l4 * 4 + r;
      float wg0 = wg_lds[o][0], wg1 = wg_lds[o][1], wg2 = wg_lds[o][2];
      float s = 0.f, q = 0.f;
#pragma unroll
      for (int st = 0; st < 8; ++st) {
        float Y = acc[t][st][r];
        float h = wg0 * h0[st] + wg1 * h1[st] + wg2 * h2[st];
        s = fmaf(cn[st], Y, s);
        q += cn[st] * Y * Y + 2.f * Y * h;
      }
#pragma unroll
      for (int m = 1; m < 16; m <<= 1) {
        s += __shfl_xor(s, m, 64);
        q += __shfl_xor(q, m, 64);
      }
      if (l15 == 0) ypart[(size_t)nb * DC + o] = make_float2(s, q);
    }
  }
}

// ---------------------------------------------------------------------------
__global__ __launch_bounds__(256)
void k_bn1f(const float2* __restrict__ ypart, const float* __restrict__ gg64,
            const float* __restrict__ W1, const float* __restrict__ gam,
            const float* __restrict__ bet, float* __restrict__ bn) {
  __shared__ float ggs[9];
  int t = threadIdx.x;
  if (t < 9) {
    float s = 0.f;
    for (int blk = 0; blk < 64; ++blk) s += gg64[blk * 16 + t];
    ggs[t] = s;
  }
  __syncthreads();
  float s = 0.f, q = 0.f;
  for (int nb = 0; nb < 64; ++nb) {
    float2 v = ypart[(size_t)nb * DC + t];
    s += v.x; q += v.y;
  }
  float wg0 = W1[t * 259 + 0], wg1 = W1[t * 259 + 1], wg2 = W1[t * 259 + 2];
  s += wg0 * ggs[6] + wg1 * ggs[7] + wg2 * ggs[8];
  q += wg0 * wg0 * ggs[0] + 2.f * wg0 * wg1 * ggs[1] + 2.f * wg0 * wg2 * ggs[2] +
       wg1 * wg1 * ggs[3] + 2.f * wg1 * wg2 * ggs[4] + wg2 * wg2 * ggs[5];
  float mu = s * kInvCnt;
  float var = q * kInvCnt - mu * mu;
  var = var < 0.f ? 0.f : var;
  float sc = gam[t] * rsqrtf(var + kEps);
  bn[t] = sc;
  bn[DC + t] = bet[t] - mu * sc;
}

// ---------------------------------------------------------------------------
// MFMA GEMM over 4 bp per block, 16x16x32 bf16 — 512 threads / 8 waves,
// round-13 loops (1-deep A prefetch; 2-deep spilled to scratch, round-15).
// XCD-aware bijective swizzle: each XCD gets a contiguous 256-group chunk
// (= one batch's ftb, 4MB -> fits the XCD-private L2).
// D layout: col = lane&15 (=s), row = (lane>>4)*4 + reg (=o).
__global__ __launch_bounds__(512, 4)
void k_gemm_full(const uint4* __restrict__ ftb, const ushort* __restrict__ W1b,
                 const ushort* __restrict__ W2b, const int* __restrict__ idxp,
                 const float* __restrict__ gxp, const float* __restrict__ bn1,
                 float2* __restrict__ part, float* __restrict__ ymax,
                 float* __restrict__ ymin) {
  __shared__ ushort x_lds[ROWS * XS];   // 75776 B; also holds 128x258 y tile
  __shared__ float bn_lds[2 * DC];

  const int bid = blockIdx.x;
  const int grp = (bid & 7) * (NG / 8) + (bid >> 3);  // NG % 8 == 0: bijective
  const int bp0 = grp * 4;
  const int b = bp0 >> 10;
  const int tid = threadIdx.x;          // 0..511
  const int lane = tid & 63;
  const int wv = tid >> 6;              // 0..7
  const int l15 = lane & 15;
  const int l4 = lane >> 4;

  bn_lds[tid] = bn1[tid];               // 512 threads == 2*DC

  // ---- gather feats: 8 threads/row, 128-B coalesced segments, 2 passes ----
  {
    int q = tid & 7;
#pragma unroll
    for (int rep = 0; rep < 2; ++rep) {
      int s = (tid >> 3) + rep * 64;
      int j = idxp[(size_t)bp0 * DNS + s];
      const uint4* src = ftb + (size_t)(b * DN + j) * (DC / 8);
      uint4* dst = (uint4*)(x_lds + (size_t)s * XS);
#pragma unroll
      for (int k = 0; k < 4; ++k) dst[q + 8 * k] = src[q + 8 * k];
    }
  }
  // ---- gx channels at k=256..258, zeros to 287 ----
  if (tid < ROWS) {
    const float* g = gxp + ((size_t)bp0 * DNS + tid) * 3;
    uint a0 = (uint)f2b(g[0]) | ((uint)f2b(g[1]) << 16);
    uint a1 = (uint)f2b(g[2]);
    uint4* drow = (uint4*)(x_lds + (size_t)tid * XS + 256);
    drow[0] = make_uint4(a0, a1, 0u, 0u);
    drow[1] = make_uint4(0u, 0u, 0u, 0u);
    drow[2] = make_uint4(0u, 0u, 0u, 0u);
    drow[3] = make_uint4(0u, 0u, 0u, 0u);
  }
  __syncthreads();

  f32x4 acc[2][8];
#pragma unroll
  for (int t = 0; t < 2; ++t)
#pragma unroll
    for (int st = 0; st < 8; ++st)
#pragma unroll
      for (int r = 0; r < 4; ++r) acc[t][st][r] = 0.f;

  const int o0 = wv * 32;
  const ushort* xbase = x_lds + (size_t)l15 * XS + l4 * 8;

  // ---- GEMM1: K = 288, 9 K-steps of 32; A prefetched one step ahead ----
  {
    const ushort* wrow[2];
#pragma unroll
    for (int t = 0; t < 2; ++t)
      wrow[t] = W1b + (size_t)(o0 + t * 16 + l15) * K1 + l4 * 8;
    bf16x8 aw[2];
#pragma unroll
    for (int t = 0; t < 2; ++t) aw[t] = *(const bf16x8*)(wrow[t]);
#pragma unroll
    for (int ks = 0; ks < NK1; ++ks) {
      bf16x8 bx[8];
#pragma unroll
      for (int st = 0; st < 8; ++st)
        bx[st] = *(const bf16x8*)(xbase + (size_t)st * 16 * XS + ks * 32);
      bf16x8 an[2];
      if (ks + 1 < NK1) {
#pragma unroll
        for (int t = 0; t < 2; ++t)
          an[t] = *(const bf16x8*)(wrow[t] + (ks + 1) * 32);
      }
      __builtin_amdgcn_s_setprio(1);
#pragma unroll
      for (int st = 0; st < 8; ++st)
#pragma unroll
        for (int t = 0; t < 2; ++t)
          acc[t][st] = __builtin_amdgcn_mfma_f32_16x16x32_bf16(aw[t], bx[st],
                                                               acc[t][st], 0, 0, 0);
      __builtin_amdgcn_s_setprio(0);
      if (ks + 1 < NK1) {
#pragma unroll
        for (int t = 0; t < 2; ++t) aw[t] = an[t];
      }
    }
  }

  // ---- bn1 + relu -> x2 (bf16) back into x_lds[s][o] (stride XS) ----
  __syncthreads();  // all GEMM1 LDS reads complete before overwrite
#pragma unroll
  for (int t = 0; t < 2; ++t) {
    int ob = o0 + t * 16 + l4 * 4;
    float sc0 = bn_lds[ob + 0], sh0 = bn_lds[DC + ob + 0];
    float sc1 = bn_lds[ob + 1], sh1 = bn_lds[DC + ob + 1];
    float sc2 = bn_lds[ob + 2], sh2 = bn_lds[DC + ob + 2];
    float sc3 = bn_lds[ob + 3], sh3 = bn_lds[DC + ob + 3];
#pragma unroll
    for (int st = 0; st < 8; ++st) {
      float v0 = fmaxf(fmaf(acc[t][st][0], sc0, sh0), 0.f);
      float v1 = fmaxf(fmaf(acc[t][st][1], sc1, sh1), 0.f);
      float v2 = fmaxf(fmaf(acc[t][st][2], sc2, sh2), 0.f);
      float v3 = fmaxf(fmaf(acc[t][st][3], sc3, sh3), 0.f);
      uint2 pk = make_uint2((uint)f2b(v0) | ((uint)f2b(v1) << 16),
                            (uint)f2b(v2) | ((uint)f2b(v3) << 16));
      int s = st * 16 + l15;
      *(uint2*)(x_lds + (size_t)s * XS + ob) = pk;
      acc[t][st][0] = 0.f; acc[t][st][1] = 0.f;
      acc[t][st][2] = 0.f; acc[t][st][3] = 0.f;
    }
  }
  __syncthreads();

  // ---- GEMM2: K = 256, 8 K-steps; A prefetched one step ahead ----
  {
    const ushort* wrow[2];
#pragma unroll
    for (int t = 0; t < 2; ++t)
      wrow[t] = W2b + (size_t)(o0 + t * 16 + l15) * K2 + l4 * 8;
    bf16x8 aw[2];
#pragma unroll
    for (int t = 0; t < 2; ++t) aw[t] = *(const bf16x8*)(wrow[t]);
#pragma unroll
    for (int ks = 0; ks < NK2; ++ks) {
      bf16x8 bx[8];
#pragma unroll
      for (int st = 0; st < 8; ++st)
        bx[st] = *(const bf16x8*)(xbase + (size_t)st * 16 * XS + ks * 32);
      bf16x8 an[2];
      if (ks + 1 < NK2) {
#pragma unroll
        for (int t = 0; t < 2; ++t)
          an[t] = *(const bf16x8*)(wrow[t] + (ks + 1) * 32);
      }
      __builtin_amdgcn_s_setprio(1);
#pragma unroll
      for (int st = 0; st < 8; ++st)
#pragma unroll
        for (int t = 0; t < 2; ++t)
          acc[t][st] = __builtin_amdgcn_mfma_f32_16x16x32_bf16(aw[t], bx[st],
                                                               acc[t][st], 0, 0, 0);
      __builtin_amdgcn_s_setprio(0);
      if (ks + 1 < NK2) {
#pragma unroll
        for (int t = 0; t < 2; ++t) aw[t] = an[t];
      }
    }
  }

  // ---- y2 -> bf16 [s][o] tile, then per-o column stats + per-bp max/min ----
  __syncthreads();
#pragma unroll
  for (int t = 0; t < 2; ++t) {
    int ob = o0 + t * 16 + l4 * 4;
#pragma unroll
    for (int st = 0; st < 8; ++st) {
      uint2 pk = make_uint2(
          (uint)f2b(acc[t][st][0]) | ((uint)f2b(acc[t][st][1]) << 16),
          (uint)f2b(acc[t][st][2]) | ((uint)f2b(acc[t][st][3]) << 16));
      int s = st * 16 + l15;
      *(uint2*)(x_lds + (size_t)s * YS + ob) = pk;
    }
  }
  __syncthreads();
  {
    // partial-sum scratch in the free tail of x_lds (bytes 66048..70144)
    float* redp = (float*)(x_lds + (size_t)ROWS * YS);
    int o = tid & 255, half = tid >> 8;   // half: rows [half*64, half*64+64)
    const ushort* col = x_lds + o;
    float s = 0.f, q = 0.f;
#pragma unroll
    for (int p2 = 0; p2 < 2; ++p2) {
      int p = half * 2 + p2;              // bp index 0..3
      float mx = -3.4e38f, mn = 3.4e38f;
#pragma unroll 8
      for (int i = 0; i < DNS; ++i) {
        float v = b2f(col[(size_t)(p * DNS + i) * YS]);
        s += v; q += v * v;
        mx = fmaxf(mx, v); mn = fminf(mn, v);
      }
      ymax[(size_t)(bp0 + p) * DC + o] = mx;
      ymin[(size_t)(bp0 + p) * DC + o] = mn;
    }
    redp[half * 256 + o] = s;
    redp[512 + half * 256 + o] = q;
    __syncthreads();
    if (tid < 256) {
      float ss = redp[tid] + redp[256 + tid];
      float qq = redp[512 + tid] + redp[768 + tid];
      part[(size_t)grp * DC + tid] = make_float2(ss, qq);
    }
  }
}

// ---------------------------------------------------------------------------
__global__ void k_reduce_bn(const float* __restrict__ part, const float* __restrict__ gam,
                            const float* __restrict__ bet, float* __restrict__ bn) {
  int o = blockIdx.x, tid = threadIdx.x;
  __shared__ float ss[256], sq[256];
  float s = 0.f, q = 0.f;
  const float2* pp = (const float2*)part;
  for (int g = tid; g < NG; g += 256) {
    float2 v = pp[(size_t)g * DC + o];
    s += v.x; q += v.y;
  }
  ss[tid] = s; sq[tid] = q;
  __syncthreads();
  for (int w = 128; w > 0; w >>= 1) {
    if (tid < w) { ss[tid] += ss[tid + w]; sq[tid] += sq[tid + w]; }
    __syncthreads();
  }
  if (tid == 0) {
    float mu = ss[0] * kInvCnt;
    float var = sq[0] * kInvCnt - mu * mu;
    var = var < 0.f ? 0.f : var;
    float sc = gam[o] * rsqrtf(var + kEps);
    bn[o] = sc;
    bn[DC + o] = bet[o] - mu * sc;
  }
}

// ---------------------------------------------------------------------------
__global__ void k_final(const float* __restrict__ ymax, const float* __restrict__ ymin,
                        const float* __restrict__ bn2, float* __restrict__ out) {
  __shared__ float tmax[32][33], tmin[32][33];
  int ot = blockIdx.x, pt = blockIdx.y, b = blockIdx.z;
  int tx = threadIdx.x, ty = threadIdx.y;  // 32 x 8
#pragma unroll
  for (int k = 0; k < 4; ++k) {
    int pr = ty + k * 8;
    size_t base = ((size_t)(b * DP) + pt * 32 + pr) * DC + ot * 32 + tx;
    tmax[pr][tx] = ymax[base];
    tmin[pr][tx] = ymin[base];
  }
  __syncthreads();
#pragma unroll
  for (int k = 0; k < 4; ++k) {
    int oc = ty + k * 8;
    int o = ot * 32 + oc;
    float sc = bn2[o], sh = bn2[DC + o];
    float m = (sc >= 0.f) ? tmax[tx][oc] : tmin[tx][oc];
    float v = fmaf(sc, m, sh);
    v = v > 0.f ? v : 0.f;
    out[((size_t)(b * DC) + o) * DP + pt * 32 + tx] = v;
  }
}

// ---------------------------------------------------------------------------
extern "C" void kernel_launch(void* const* d_in, const int* in_sizes, int n_in,
                              void* d_out, int out_size, void* d_ws, size_t ws_size,
                              hipStream_t stream) {
  const float* xyz   = (const float*)d_in[0];
  const float* feats = (const float*)d_in[1];
  const float* rot   = (const float*)d_in[2];
  const float* W1    = (const float*)d_in[3];
  const float* g1    = (const float*)d_in[4];
  const float* b1    = (const float*)d_in[5];
  const float* W2    = (const float*)d_in[6];
  const float* g2    = (const float*)d_in[7];
  const float* b2    = (const float*)d_in[8];
  float* out = (float*)d_out;

  float* ws = (float*)d_ws;
  uint*   ftb_u  = (uint*)(ws + OF_FEATST);
  uint4*  ftb    = (uint4*)(ws + OF_FEATST);
  ushort* W1b    = (ushort*)(ws + OF_W1B);
  ushort* W2b    = (ushort*)(ws + OF_W2B);
  int*    idxp   = (int*)(ws + OF_IDX);
  float*  gxp    = ws + OF_GX;
  float2* partp  = (float2*)(ws + OF_PART);
  float*  ymaxp  = ws + OF_YMAX;
  float*  yminp  = ws + OF_YMIN;
  float*  bn1p   = ws + OF_BN1;
  float*  bn2p   = ws + OF_BN2;
  float*  cntzp  = ws + OF_CNTZ;
  float*  gwzp   = ws + OF_GWZ;
  float*  gg64p  = ws + OF_GG64;
  float2* yprtp  = (float2*)(ws + OF_YPRT);

  k_prep<<<4640, 256, 0, stream>>>(feats, ftb_u, W1, W1b, W2, W2b,
                                   xyz, rot, idxp, gxp);

  // ---- bn1 stats via point-factored algebra (Y-GEMM over unique points) ----
  k_count<<<64, 256, 0, stream>>>(idxp, gxp, cntzp, gwzp, gg64p);
  k_ygemm<<<64, 256, 0, stream>>>(ftb, W1b, W1, cntzp, gwzp, yprtp);
  k_bn1f<<<1, 256, 0, stream>>>(yprtp, gg64p, W1, g1, b1, bn1p);

  // ---- fused GEMM1+bn1+relu+GEMM2 + y2 stats/max/min ----
  k_gemm_full<<<NG, 512, 0, stream>>>(ftb, W1b, W2b, idxp, gxp, bn1p, partp,
                                      ymaxp, yminp);
  k_reduce_bn<<<DC, 256, 0, stream>>>((const float*)partp, g2, b2, bn2p);
  k_final<<<dim3(DC / 32, DP / 32, DB), dim3(32, 8), 0, stream>>>(ymaxp, yminp, bn2p, out);
}

// Round 17
// 143.081 us; speedup vs baseline: 1.2849x; 1.0836x over previous
//
#include <hip/hip_runtime.h>
#include <hip/hip_bf16.h>

#define DB 8
#define DN 1024
#define DP 1024
#define DC 256
#define DNS 32
#define DBP (DB * DP)
#define K1 288   // padded GEMM1 K (256 feats + 3 gx + 29 zeros)
#define K2 256
#define XS 296   // x_lds row stride in bf16 elems (592 B; 148 dwords == 20 mod 32)
#define YS 258   // epilogue y-tile row stride in bf16 (129 dwords == 1 mod 32)
#define ROWS 128 // 4 bp per block
#define NG (DBP / 4)
#define NK1 (K1 / 32)  // 9
#define NK2 (K2 / 32)  // 8
#define NSL 32   // cnt slices per batch (256 k_count blocks)

constexpr float kRadius = 0.05f;
constexpr float kR2 = kRadius * kRadius;
constexpr float kHmin = -0.02f;
constexpr float kHmax = 0.04f;
constexpr float kEps = 1e-5f;
constexpr float kInvCnt = 1.0f / (float)(DB * DP * DNS);

typedef __bf16 bf16x8 __attribute__((ext_vector_type(8)));
typedef float f32x4 __attribute__((ext_vector_type(4)));
static_assert(sizeof(bf16x8) == 16, "bf16x8 must be 16B");

// ---- workspace layout (in floats) ----
constexpr size_t OF_FEATST = 0;                                   // B*N*C bf16
constexpr size_t OF_W1B  = OF_FEATST + (size_t)DB * DN * DC / 2;  // DC*K1 bf16
constexpr size_t OF_W2B  = OF_W1B + (size_t)DC * K1 / 2;          // DC*K2 bf16
constexpr size_t OF_IDX  = OF_W2B + (size_t)DC * K2 / 2;          // BP*NS int32
constexpr size_t OF_GX   = OF_IDX + (size_t)DBP * DNS;            // BP*NS*3
constexpr size_t OF_PART = OF_GX + (size_t)DBP * DNS * 3;         // NG*C*2
constexpr size_t OF_YMAX = OF_PART + (size_t)DBP * DC * 2;        // BP*C
constexpr size_t OF_YMIN = OF_YMAX + (size_t)DBP * DC;            // BP*C
constexpr size_t OF_BN1  = OF_YMIN + (size_t)DBP * DC;            // 512
constexpr size_t OF_BN2  = OF_BN1 + 512;                          // 512
// ---- stats scratch ALIASED onto part/ymax region (r8 trick): the stats
// phase completes before k_gemm_full writes part/ymax/ymin (stream order).
constexpr size_t OF_CNTZ = OF_PART;                               // 256*DN
constexpr size_t OF_GWZ  = OF_CNTZ + (size_t)256 * DN;            // 256*3*DN
constexpr size_t OF_GG   = OF_GWZ + (size_t)256 * 3 * DN;         // 256*16
constexpr size_t OF_YPRT = OF_GG + 4096;                          // 64*DC*2

__device__ inline ushort f2b(float x) {
  union { __hip_bfloat16 h; ushort u; } c;
  c.h = __float2bfloat16(x);
  return c.u;
}
__device__ inline float b2f(ushort u) {
  union { uint u; float f; } c;
  c.u = (uint)u << 16;
  return c.f;
}

// ---------------------------------------------------------------------------
// fused pre-pass: [0,2048) transpose feats; [2048,2336) W1 prep; [2336,2592)
// W2 prep; [2592,4640) cylinder query (4 bp per block, one per wave).
__global__ __launch_bounds__(256)
void k_prep(const float* __restrict__ f, uint* __restrict__ ftb,
            const float* __restrict__ W1, ushort* __restrict__ W1b,
            const float* __restrict__ W2, ushort* __restrict__ W2b,
            const float* __restrict__ xyz, const float* __restrict__ rot,
            int* __restrict__ idxp, float* __restrict__ gxp) {
  __shared__ float t[32][33];
  __shared__ int sidx[4][DNS];
  __shared__ float srot[4][9], sc[4][3];
  int blk = blockIdx.x;
  int tid = threadIdx.x;
  if (blk < 2048) {
    int ct = blk & 7, nt = (blk >> 3) & 31, b = blk >> 8;
    int tx = tid & 31, ty = tid >> 5;
#pragma unroll
    for (int k = 0; k < 4; ++k) {
      int c = ct * 32 + ty + k * 8;
      t[ty + k * 8][tx] = f[((size_t)b * DC + c) * DN + nt * 32 + tx];
    }
    __syncthreads();
    uint* dst = ftb + (size_t)b * DN * (DC / 2);
#pragma unroll
    for (int it = 0; it < 2; ++it) {
      int idx = it * 256 + tid;
      int nl = idx >> 4, cp = idx & 15;
      uint v = (uint)f2b(t[2 * cp][nl]) | ((uint)f2b(t[2 * cp + 1][nl]) << 16);
      dst[(size_t)(nt * 32 + nl) * (DC / 2) + ct * 16 + cp] = v;
    }
  } else if (blk < 2336) {
    int gid = (blk - 2048) * 256 + tid;
    if (gid < DC * K1) {
      int o = gid / K1, kp = gid - o * K1;
      float v = 0.f;
      if (kp < 256) v = W1[o * 259 + 3 + kp];
      else if (kp < 259) v = W1[o * 259 + (kp - 256)];
      W1b[gid] = f2b(v);
    }
  } else if (blk < 2592) {
    int gid = (blk - 2336) * 256 + tid;
    if (gid < DC * K2) W2b[gid] = f2b(W2[gid]);
  } else {
    int wv = tid >> 6;
    int lane = tid & 63;
    int bp = (blk - 2592) * 4 + wv;
    int b = bp >> 10;
    if (lane < DNS) sidx[wv][lane] = 0;
    if (lane < 9) srot[wv][lane] = rot[(size_t)bp * 9 + lane];
    if (lane < 3) sc[wv][lane] = xyz[(size_t)bp * 3 + lane];
    float r00 = srot[wv][0], r01 = srot[wv][1], r02 = srot[wv][2];
    float r10 = srot[wv][3], r11 = srot[wv][4], r12 = srot[wv][5];
    float r20 = srot[wv][6], r21 = srot[wv][7], r22 = srot[wv][8];
    float cx = sc[wv][0], cy = sc[wv][1], cz = sc[wv][2];
    const float* xb = xyz + (size_t)b * DN * 3;
    int cnt = 0;
    for (int ch = 0; ch < DN / 64 && cnt < DNS; ++ch) {
      int n = ch * 64 + lane;
      float dx = xb[n * 3 + 0] - cx, dy = xb[n * 3 + 1] - cy, dz = xb[n * 3 + 2] - cz;
      float lx = dx * r00 + dy * r10 + dz * r20;
      float ly = dx * r01 + dy * r11 + dz * r21;
      float lz = dx * r02 + dy * r12 + dz * r22;
      bool m = (ly * ly + lz * lz < kR2) && (lx > kHmin) && (lx < kHmax);
      unsigned long long bal = __ballot(m);
      int rank = cnt + __popcll(bal & ((1ull << lane) - 1ull));
      if (m && rank < DNS) sidx[wv][rank] = n;
      cnt += __popcll(bal);
    }
    if (lane < DNS) {
      int j = sidx[wv][lane];
      idxp[(size_t)bp * DNS + lane] = j;
      float gx = (xb[j * 3 + 0] - cx) / kRadius;
      float gy = (xb[j * 3 + 1] - cy) / kRadius;
      float gz = (xb[j * 3 + 2] - cz) / kRadius;
      float* gp = gxp + ((size_t)bp * DNS + lane) * 3;
      gp[0] = gx * r00 + gy * r10 + gz * r20;
      gp[1] = gx * r01 + gy * r11 + gz * r21;
      gp[2] = gx * r02 + gy * r12 + gz * r22;
    }
  }
}

// ---------------------------------------------------------------------------
// per-point counts + weighted gx sums via LDS histogram, plain-stored into
// per-block slices. 256 blocks x 256 thr (32 slices/batch, 1024 samples each).
// gg[blk*16+v]: v=0..5 gx 2nd moments, 6..8 gx sums.
__global__ __launch_bounds__(256)
void k_count(const int* __restrict__ idxp, const float* __restrict__ gxp,
             float* __restrict__ cntz, float* __restrict__ gwz,
             float* __restrict__ gg) {
  __shared__ float h0[DN], h1[DN], h2[DN], h3[DN];
  int t = threadIdx.x;
  int blk = blockIdx.x;          // 0..255; b = blk>>5, slice = blk&31
  for (int i = t; i < DN; i += 256) {
    h0[i] = 0.f; h1[i] = 0.f; h2[i] = 0.f; h3[i] = 0.f;
  }
  __syncthreads();
  float p[9] = {0.f, 0.f, 0.f, 0.f, 0.f, 0.f, 0.f, 0.f, 0.f};
#pragma unroll
  for (int r = 0; r < 4; ++r) {
    int sid = blk * 1024 + r * 256 + t;
    int j = idxp[sid];
    const float* g = gxp + (size_t)sid * 3;
    float g0 = g[0], g1 = g[1], g2 = g[2];
    atomicAdd(&h0[j], 1.f);
    atomicAdd(&h1[j], g0);
    atomicAdd(&h2[j], g1);
    atomicAdd(&h3[j], g2);
    p[0] += g0 * g0; p[1] += g0 * g1; p[2] += g0 * g2;
    p[3] += g1 * g1; p[4] += g1 * g2; p[5] += g2 * g2;
    p[6] += g0; p[7] += g1; p[8] += g2;
  }
  __syncthreads();
  for (int i = t; i < DN; i += 256) {
    cntz[(size_t)blk * DN + i] = h0[i];
    gwz[((size_t)blk * 3 + 0) * DN + i] = h1[i];
    gwz[((size_t)blk * 3 + 1) * DN + i] = h2[i];
    gwz[((size_t)blk * 3 + 2) * DN + i] = h3[i];
  }
  __shared__ float sgg[4][9];
#pragma unroll
  for (int v = 0; v < 9; ++v) {
    float sv = p[v];
#pragma unroll
    for (int m = 1; m < 64; m <<= 1) sv += __shfl_xor(sv, m, 64);
    if ((t & 63) == 0) sgg[t >> 6][v] = sv;
  }
  __syncthreads();
  if (t < 9) gg[blk * 16 + t] = sgg[0][t] + sgg[1][t] + sgg[2][t] + sgg[3][t];
}

// ---------------------------------------------------------------------------
// Yf = W1_feat x feats over unique points (K=256, no gather), fused weighted
// stats. 128 blocks x 256 thr: block = (row = b*8 + n-range) x (o-half).
__global__ __launch_bounds__(256)
void k_ygemm(const uint4* __restrict__ ftb, const ushort* __restrict__ W1b,
             const float* __restrict__ W1, const float* __restrict__ cntz,
             const float* __restrict__ gwz, float2* __restrict__ ypart) {
  __shared__ ushort x_lds[ROWS * XS];
  __shared__ float c_lds[ROWS];
  __shared__ float g_lds[3][ROWS];
  __shared__ float wg_lds[DC][3];

  const int nb = blockIdx.x;       // 0..127
  const int row = nb >> 1;         // 0..63
  const int oh = nb & 1;
  const int b = row >> 3;
  const int n0 = (row & 7) * ROWS;
  const int tid = threadIdx.x;
  const int lane = tid & 63;
  const int wv = tid >> 6;
  const int l15 = lane & 15;
  const int l4 = lane >> 4;

  {
    const uint4* src = ftb + ((size_t)b * DN + n0) * (DC / 8);
    for (int idx = tid; idx < ROWS * 32; idx += 256) {
      int rrow = idx >> 5, col = idx & 31;
      ((uint4*)(x_lds + (size_t)rrow * XS))[col] = src[rrow * 32 + col];
    }
  }
  if (tid < ROWS) {
    float c = 0.f, g0 = 0.f, g1 = 0.f, g2 = 0.f;
    for (int s = 0; s < NSL; ++s) {
      int blk = b * NSL + s;
      c += cntz[(size_t)blk * DN + n0 + tid];
      g0 += gwz[((size_t)blk * 3 + 0) * DN + n0 + tid];
      g1 += gwz[((size_t)blk * 3 + 1) * DN + n0 + tid];
      g2 += gwz[((size_t)blk * 3 + 2) * DN + n0 + tid];
    }
    c_lds[tid] = c; g_lds[0][tid] = g0; g_lds[1][tid] = g1; g_lds[2][tid] = g2;
  }
  {
    wg_lds[tid][0] = W1[tid * 259 + 0];
    wg_lds[tid][1] = W1[tid * 259 + 1];
    wg_lds[tid][2] = W1[tid * 259 + 2];
  }
  __syncthreads();

  f32x4 acc[2][8];
#pragma unroll
  for (int t = 0; t < 2; ++t)
#pragma unroll
    for (int st = 0; st < 8; ++st)
#pragma unroll
      for (int r = 0; r < 4; ++r) acc[t][st][r] = 0.f;

  const int o0 = oh * 128 + wv * 32;
  const ushort* xbase = x_lds + (size_t)l15 * XS + l4 * 8;
  {
    const ushort* wrow[2];
#pragma unroll
    for (int t = 0; t < 2; ++t)
      wrow[t] = W1b + (size_t)(o0 + t * 16 + l15) * K1 + l4 * 8;
#pragma unroll
    for (int ks = 0; ks < 8; ++ks) {
      bf16x8 bx[8], aw[2];
#pragma unroll
      for (int st = 0; st < 8; ++st)
        bx[st] = *(const bf16x8*)(xbase + (size_t)st * 16 * XS + ks * 32);
#pragma unroll
      for (int t = 0; t < 2; ++t) aw[t] = *(const bf16x8*)(wrow[t] + ks * 32);
#pragma unroll
      for (int st = 0; st < 8; ++st)
#pragma unroll
        for (int t = 0; t < 2; ++t)
          acc[t][st] = __builtin_amdgcn_mfma_f32_16x16x32_bf16(aw[t], bx[st],
                                                               acc[t][st], 0, 0, 0);
    }
  }

  float cn[8], h0[8], h1[8], h2[8];
#pragma unroll
  for (int st = 0; st < 8; ++st) {
    int n = st * 16 + l15;
    cn[st] = c_lds[n]; h0[st] = g_lds[0][n]; h1[st] = g_lds[1][n]; h2[st] = g_lds[2][n];
  }
#pragma unroll
  for (int t = 0; t < 2; ++t) {
#pragma unroll
    for (int r = 0; r < 4; ++r) {
      int o = o0 + t * 16 + l4 * 4 + r;
      float wg0 = wg_lds[o][0], wg1 = wg_lds[o][1], wg2 = wg_lds[o][2];
      float s = 0.f, q = 0.f;
#pragma unroll
      for (int st = 0; st < 8; ++st) {
        float Y = acc[t][st][r];
        float h = wg0 * h0[st] + wg1 * h1[st] + wg2 * h2[st];
        s = fmaf(cn[st], Y, s);
        q += cn[st] * Y * Y + 2.f * Y * h;
      }
#pragma unroll
      for (int m = 1; m < 16; m <<= 1) {
        s += __shfl_xor(s, m, 64);
        q += __shfl_xor(q, m, 64);
      }
      if (l15 == 0) ypart[(size_t)row * DC + o] = make_float2(s, q);
    }
  }
}

// ---------------------------------------------------------------------------
__global__ __launch_bounds__(256)
void k_bn1f(const float2* __restrict__ ypart, const float* __restrict__ gg,
            const float* __restrict__ W1, const float* __restrict__ gam,
            const float* __restrict__ bet, float* __restrict__ bn) {
  __shared__ float ggs[9];
  int t = threadIdx.x;
  if (t < 9) {
    float s = 0.f;
    for (int blk = 0; blk < 256; ++blk) s += gg[blk * 16 + t];
    ggs[t] = s;
  }
  __syncthreads();
  float s = 0.f, q = 0.f;
  for (int nb = 0; nb < 64; ++nb) {
    float2 v = ypart[(size_t)nb * DC + t];
    s += v.x; q += v.y;
  }
  float wg0 = W1[t * 259 + 0], wg1 = W1[t * 259 + 1], wg2 = W1[t * 259 + 2];
  s += wg0 * ggs[6] + wg1 * ggs[7] + wg2 * ggs[8];
  q += wg0 * wg0 * ggs[0] + 2.f * wg0 * wg1 * ggs[1] + 2.f * wg0 * wg2 * ggs[2] +
       wg1 * wg1 * ggs[3] + 2.f * wg1 * wg2 * ggs[4] + wg2 * wg2 * ggs[5];
  float mu = s * kInvCnt;
  float var = q * kInvCnt - mu * mu;
  var = var < 0.f ? 0.f : var;
  float sc = gam[t] * rsqrtf(var + kEps);
  bn[t] = sc;
  bn[DC + t] = bet[t] - mu * sc;
}

// ---------------------------------------------------------------------------
// MFMA GEMM over 4 bp per block, 16x16x32 bf16 — 512 threads / 8 waves,
// r13 loops + XCD-aware bijective swizzle (r16 measured best: 87.5 us,
// VGPR 64 + 64 AGPR = exactly the 128-reg / 4-wave-per-SIMD cliff).
__global__ __launch_bounds__(512, 4)
void k_gemm_full(const uint4* __restrict__ ftb, const ushort* __restrict__ W1b,
                 const ushort* __restrict__ W2b, const int* __restrict__ idxp,
                 const float* __restrict__ gxp, const float* __restrict__ bn1,
                 float2* __restrict__ part, float* __restrict__ ymax,
                 float* __restrict__ ymin) {
  __shared__ ushort x_lds[ROWS * XS];   // 75776 B; also holds 128x258 y tile
  __shared__ float bn_lds[2 * DC];

  const int bid = blockIdx.x;
  const int grp = (bid & 7) * (NG / 8) + (bid >> 3);  // NG % 8 == 0: bijective
  const int bp0 = grp * 4;
  const int b = bp0 >> 10;
  const int tid = threadIdx.x;          // 0..511
  const int lane = tid & 63;
  const int wv = tid >> 6;              // 0..7
  const int l15 = lane & 15;
  const int l4 = lane >> 4;

  bn_lds[tid] = bn1[tid];               // 512 threads == 2*DC

  // ---- gather feats: 8 threads/row, 128-B coalesced segments, 2 passes ----
  {
    int q = tid & 7;
#pragma unroll
    for (int rep = 0; rep < 2; ++rep) {
      int s = (tid >> 3) + rep * 64;
      int j = idxp[(size_t)bp0 * DNS + s];
      const uint4* src = ftb + (size_t)(b * DN + j) * (DC / 8);
      uint4* dst = (uint4*)(x_lds + (size_t)s * XS);
#pragma unroll
      for (int k = 0; k < 4; ++k) dst[q + 8 * k] = src[q + 8 * k];
    }
  }
  // ---- gx channels at k=256..258, zeros to 287 ----
  if (tid < ROWS) {
    const float* g = gxp + ((size_t)bp0 * DNS + tid) * 3;
    uint a0 = (uint)f2b(g[0]) | ((uint)f2b(g[1]) << 16);
    uint a1 = (uint)f2b(g[2]);
    uint4* drow = (uint4*)(x_lds + (size_t)tid * XS + 256);
    drow[0] = make_uint4(a0, a1, 0u, 0u);
    drow[1] = make_uint4(0u, 0u, 0u, 0u);
    drow[2] = make_uint4(0u, 0u, 0u, 0u);
    drow[3] = make_uint4(0u, 0u, 0u, 0u);
  }
  __syncthreads();

  f32x4 acc[2][8];
#pragma unroll
  for (int t = 0; t < 2; ++t)
#pragma unroll
    for (int st = 0; st < 8; ++st)
#pragma unroll
      for (int r = 0; r < 4; ++r) acc[t][st][r] = 0.f;

  const int o0 = wv * 32;
  const ushort* xbase = x_lds + (size_t)l15 * XS + l4 * 8;

  // ---- GEMM1: K = 288, 9 K-steps of 32; A prefetched one step ahead ----
  {
    const ushort* wrow[2];
#pragma unroll
    for (int t = 0; t < 2; ++t)
      wrow[t] = W1b + (size_t)(o0 + t * 16 + l15) * K1 + l4 * 8;
    bf16x8 aw[2];
#pragma unroll
    for (int t = 0; t < 2; ++t) aw[t] = *(const bf16x8*)(wrow[t]);
#pragma unroll
    for (int ks = 0; ks < NK1; ++ks) {
      bf16x8 bx[8];
#pragma unroll
      for (int st = 0; st < 8; ++st)
        bx[st] = *(const bf16x8*)(xbase + (size_t)st * 16 * XS + ks * 32);
      bf16x8 an[2];
      if (ks + 1 < NK1) {
#pragma unroll
        for (int t = 0; t < 2; ++t)
          an[t] = *(const bf16x8*)(wrow[t] + (ks + 1) * 32);
      }
      __builtin_amdgcn_s_setprio(1);
#pragma unroll
      for (int st = 0; st < 8; ++st)
#pragma unroll
        for (int t = 0; t < 2; ++t)
          acc[t][st] = __builtin_amdgcn_mfma_f32_16x16x32_bf16(aw[t], bx[st],
                                                               acc[t][st], 0, 0, 0);
      __builtin_amdgcn_s_setprio(0);
      if (ks + 1 < NK1) {
#pragma unroll
        for (int t = 0; t < 2; ++t) aw[t] = an[t];
      }
    }
  }

  // ---- bn1 + relu -> x2 (bf16) back into x_lds[s][o] (stride XS) ----
  __syncthreads();  // all GEMM1 LDS reads complete before overwrite
#pragma unroll
  for (int t = 0; t < 2; ++t) {
    int ob = o0 + t * 16 + l4 * 4;
    float sc0 = bn_lds[ob + 0], sh0 = bn_lds[DC + ob + 0];
    float sc1 = bn_lds[ob + 1], sh1 = bn_lds[DC + ob + 1];
    float sc2 = bn_lds[ob + 2], sh2 = bn_lds[DC + ob + 2];
    float sc3 = bn_lds[ob + 3], sh3 = bn_lds[DC + ob + 3];
#pragma unroll
    for (int st = 0; st < 8; ++st) {
      float v0 = fmaxf(fmaf(acc[t][st][0], sc0, sh0), 0.f);
      float v1 = fmaxf(fmaf(acc[t][st][1], sc1, sh1), 0.f);
      float v2 = fmaxf(fmaf(acc[t][st][2], sc2, sh2), 0.f);
      float v3 = fmaxf(fmaf(acc[t][st][3], sc3, sh3), 0.f);
      uint2 pk = make_uint2((uint)f2b(v0) | ((uint)f2b(v1) << 16),
                            (uint)f2b(v2) | ((uint)f2b(v3) << 16));
      int s = st * 16 + l15;
      *(uint2*)(x_lds + (size_t)s * XS + ob) = pk;
      acc[t][st][0] = 0.f; acc[t][st][1] = 0.f;
      acc[t][st][2] = 0.f; acc[t][st][3] = 0.f;
    }
  }
  __syncthreads();

  // ---- GEMM2: K = 256, 8 K-steps; A prefetched one step ahead ----
  {
    const ushort* wrow[2];
#pragma unroll
    for (int t = 0; t < 2; ++t)
      wrow[t] = W2b + (size_t)(o0 + t * 16 + l15) * K2 + l4 * 8;
    bf16x8 aw[2];
#pragma unroll
    for (int t = 0; t < 2; ++t) aw[t] = *(const bf16x8*)(wrow[t]);
#pragma unroll
    for (int ks = 0; ks < NK2; ++ks) {
      bf16x8 bx[8];
#pragma unroll
      for (int st = 0; st < 8; ++st)
        bx[st] = *(const bf16x8*)(xbase + (size_t)st * 16 * XS + ks * 32);
      bf16x8 an[2];
      if (ks + 1 < NK2) {
#pragma unroll
        for (int t = 0; t < 2; ++t)
          an[t] = *(const bf16x8*)(wrow[t] + (ks + 1) * 32);
      }
      __builtin_amdgcn_s_setprio(1);
#pragma unroll
      for (int st = 0; st < 8; ++st)
#pragma unroll
        for (int t = 0; t < 2; ++t)
          acc[t][st] = __builtin_amdgcn_mfma_f32_16x16x32_bf16(aw[t], bx[st],
                                                               acc[t][st], 0, 0, 0);
      __builtin_amdgcn_s_setprio(0);
      if (ks + 1 < NK2) {
#pragma unroll
        for (int t = 0; t < 2; ++t) aw[t] = an[t];
      }
    }
  }

  // ---- y2 -> bf16 [s][o] tile, then per-o column stats + per-bp max/min ----
  __syncthreads();
#pragma unroll
  for (int t = 0; t < 2; ++t) {
    int ob = o0 + t * 16 + l4 * 4;
#pragma unroll
    for (int st = 0; st < 8; ++st) {
      uint2 pk = make_uint2(
          (uint)f2b(acc[t][st][0]) | ((uint)f2b(acc[t][st][1]) << 16),
          (uint)f2b(acc[t][st][2]) | ((uint)f2b(acc[t][st][3]) << 16));
      int s = st * 16 + l15;
      *(uint2*)(x_lds + (size_t)s * YS + ob) = pk;
    }
  }
  __syncthreads();
  {
    // partial-sum scratch in the free tail of x_lds (bytes 66048..70144)
    float* redp = (float*)(x_lds + (size_t)ROWS * YS);
    int o = tid & 255, half = tid >> 8;   // half: rows [half*64, half*64+64)
    const ushort* col = x_lds + o;
    float s = 0.f, q = 0.f;
#pragma unroll
    for (int p2 = 0; p2 < 2; ++p2) {
      int p = half * 2 + p2;              // bp index 0..3
      float mx = -3.4e38f, mn = 3.4e38f;
#pragma unroll 8
      for (int i = 0; i < DNS; ++i) {
        float v = b2f(col[(size_t)(p * DNS + i) * YS]);
        s += v; q += v * v;
        mx = fmaxf(mx, v); mn = fminf(mn, v);
      }
      ymax[(size_t)(bp0 + p) * DC + o] = mx;
      ymin[(size_t)(bp0 + p) * DC + o] = mn;
    }
    redp[half * 256 + o] = s;
    redp[512 + half * 256 + o] = q;
    __syncthreads();
    if (tid < 256) {
      float ss = redp[tid] + redp[256 + tid];
      float qq = redp[512 + tid] + redp[768 + tid];
      part[(size_t)grp * DC + tid] = make_float2(ss, qq);
    }
  }
}

// ---------------------------------------------------------------------------
__global__ void k_reduce_bn(const float* __restrict__ part, const float* __restrict__ gam,
                            const float* __restrict__ bet, float* __restrict__ bn) {
  int o = blockIdx.x, tid = threadIdx.x;
  __shared__ float ss[256], sq[256];
  float s = 0.f, q = 0.f;
  const float2* pp = (const float2*)part;
  for (int g = tid; g < NG; g += 256) {
    float2 v = pp[(size_t)g * DC + o];
    s += v.x; q += v.y;
  }
  ss[tid] = s; sq[tid] = q;
  __syncthreads();
  for (int w = 128; w > 0; w >>= 1) {
    if (tid < w) { ss[tid] += ss[tid + w]; sq[tid] += sq[tid + w]; }
    __syncthreads();
  }
  if (tid == 0) {
    float mu = ss[0] * kInvCnt;
    float var = sq[0] * kInvCnt - mu * mu;
    var = var < 0.f ? 0.f : var;
    float sc = gam[o] * rsqrtf(var + kEps);
    bn[o] = sc;
    bn[DC + o] = bet[o] - mu * sc;
  }
}

// ---------------------------------------------------------------------------
__global__ void k_final(const float* __restrict__ ymax, const float* __restrict__ ymin,
                        const float* __restrict__ bn2, float* __restrict__ out) {
  __shared__ float tmax[32][33], tmin[32][33];
  int ot = blockIdx.x, pt = blockIdx.y, b = blockIdx.z;
  int tx = threadIdx.x, ty = threadIdx.y;  // 32 x 8
#pragma unroll
  for (int k = 0; k < 4; ++k) {
    int pr = ty + k * 8;
    size_t base = ((size_t)(b * DP) + pt * 32 + pr) * DC + ot * 32 + tx;
    tmax[pr][tx] = ymax[base];
    tmin[pr][tx] = ymin[base];
  }
  __syncthreads();
#pragma unroll
  for (int k = 0; k < 4; ++k) {
    int oc = ty + k * 8;
    int o = ot * 32 + oc;
    float sc = bn2[o], sh = bn2[DC + o];
    float m = (sc >= 0.f) ? tmax[tx][oc] : tmin[tx][oc];
    float v = fmaf(sc, m, sh);
    v = v > 0.f ? v : 0.f;
    out[((size_t)(b * DC) + o) * DP + pt * 32 + tx] = v;
  }
}

// ---------------------------------------------------------------------------
extern "C" void kernel_launch(void* const* d_in, const int* in_sizes, int n_in,
                              void* d_out, int out_size, void* d_ws, size_t ws_size,
                              hipStream_t stream) {
  const float* xyz   = (const float*)d_in[0];
  const float* feats = (const float*)d_in[1];
  const float* rot   = (const float*)d_in[2];
  const float* W1    = (const float*)d_in[3];
  const float* g1    = (const float*)d_in[4];
  const float* b1    = (const float*)d_in[5];
  const float* W2    = (const float*)d_in[6];
  const float* g2    = (const float*)d_in[7];
  const float* b2    = (const float*)d_in[8];
  float* out = (float*)d_out;

  float* ws = (float*)d_ws;
  uint*   ftb_u  = (uint*)(ws + OF_FEATST);
  uint4*  ftb    = (uint4*)(ws + OF_FEATST);
  ushort* W1b    = (ushort*)(ws + OF_W1B);
  ushort* W2b    = (ushort*)(ws + OF_W2B);
  int*    idxp   = (int*)(ws + OF_IDX);
  float*  gxp    = ws + OF_GX;
  float2* partp  = (float2*)(ws + OF_PART);
  float*  ymaxp  = ws + OF_YMAX;
  float*  yminp  = ws + OF_YMIN;
  float*  bn1p   = ws + OF_BN1;
  float*  bn2p   = ws + OF_BN2;
  float*  cntzp  = ws + OF_CNTZ;   // aliased onto part/ymax region
  float*  gwzp   = ws + OF_GWZ;
  float*  ggp    = ws + OF_GG;
  float2* yprtp  = (float2*)(ws + OF_YPRT);

  k_prep<<<4640, 256, 0, stream>>>(feats, ftb_u, W1, W1b, W2, W2b,
                                   xyz, rot, idxp, gxp);

  // ---- bn1 stats via point-factored algebra (Y-GEMM over unique points) ----
  k_count<<<256, 256, 0, stream>>>(idxp, gxp, cntzp, gwzp, ggp);
  k_ygemm<<<128, 256, 0, stream>>>(ftb, W1b, W1, cntzp, gwzp, yprtp);
  k_bn1f<<<1, 256, 0, stream>>>(yprtp, ggp, W1, g1, b1, bn1p);

  // ---- fused GEMM1+bn1+relu+GEMM2 + y2 stats/max/min ----
  k_gemm_full<<<NG, 512, 0, stream>>>(ftb, W1b, W2b, idxp, gxp, bn1p, partp,
                                      ymaxp, yminp);
  k_reduce_bn<<<DC, 256, 0, stream>>>((const float*)partp, g2, b2, bn2p);
  k_final<<<dim3(DC / 32, DP / 32, DB), dim3(32, 8), 0, stream>>>(ymaxp, yminp, bn2p, out);
}

// Round 18
// 141.325 us; speedup vs baseline: 1.3008x; 1.0124x over previous
//
#include <hip/hip_runtime.h>
#include <hip/hip_bf16.h>

#define DB 8
#define DN 1024
#define DP 1024
#define DC 256
#define DNS 32
#define DBP (DB * DP)
#define K1 288   // padded GEMM1 K (256 feats + 3 gx + 29 zeros)
#define K2 256
#define XS 296   // x_lds row stride in bf16 elems (592 B; 148 dwords == 20 mod 32)
#define YS 258   // epilogue y-tile row stride in bf16 (129 dwords == 1 mod 32)
#define ROWS 128 // 4 bp per block
#define NG (DBP / 4)
#define NK1 (K1 / 32)  // 9
#define NK2 (K2 / 32)  // 8
#define NSL 32   // cnt slices per batch (256 k_count blocks)

constexpr float kRadius = 0.05f;
constexpr float kR2 = kRadius * kRadius;
constexpr float kHmin = -0.02f;
constexpr float kHmax = 0.04f;
constexpr float kEps = 1e-5f;
constexpr float kInvCnt = 1.0f / (float)(DB * DP * DNS);

typedef __bf16 bf16x8 __attribute__((ext_vector_type(8)));
typedef float f32x4 __attribute__((ext_vector_type(4)));
static_assert(sizeof(bf16x8) == 16, "bf16x8 must be 16B");

// ---- workspace layout (in floats) ----
constexpr size_t OF_FEATST = 0;                                   // B*N*C bf16
constexpr size_t OF_W1B  = OF_FEATST + (size_t)DB * DN * DC / 2;  // DC*K1 bf16
constexpr size_t OF_W2B  = OF_W1B + (size_t)DC * K1 / 2;          // DC*K2 bf16
constexpr size_t OF_IDX  = OF_W2B + (size_t)DC * K2 / 2;          // BP*NS int32
constexpr size_t OF_GX   = OF_IDX + (size_t)DBP * DNS;            // BP*NS*3
constexpr size_t OF_PART = OF_GX + (size_t)DBP * DNS * 3;         // NG*C*2
constexpr size_t OF_YMAX = OF_PART + (size_t)NG * DC * 2;         // BP*C bf16
constexpr size_t OF_YMIN = OF_YMAX + (size_t)DBP * DC / 2;        // BP*C bf16
constexpr size_t OF_BN1  = OF_YMIN + (size_t)DBP * DC / 2;        // 512
constexpr size_t OF_BN2  = OF_BN1 + 512;                          // 512
// ---- stats scratch ALIASED onto part/ymax region (r8 trick): the stats
// phase completes before k_gemm_full writes part/ymax/ymin (stream order).
constexpr size_t OF_CNTZ = OF_PART;                               // 256*DN
constexpr size_t OF_GWZ  = OF_CNTZ + (size_t)256 * DN;            // 256*3*DN
constexpr size_t OF_GG   = OF_GWZ + (size_t)256 * 3 * DN;         // 256*16
constexpr size_t OF_YPRT = OF_GG + 4096;                          // 64*DC*2

__device__ inline ushort f2b(float x) {
  union { __hip_bfloat16 h; ushort u; } c;
  c.h = __float2bfloat16(x);
  return c.u;
}
__device__ inline float b2f(ushort u) {
  union { uint u; float f; } c;
  c.u = (uint)u << 16;
  return c.f;
}

// ---------------------------------------------------------------------------
// fused pre-pass: [0,2048) transpose feats; [2048,2336) W1 prep; [2336,2592)
// W2 prep; [2592,4640) cylinder query (4 bp per block, one per wave).
__global__ __launch_bounds__(256)
void k_prep(const float* __restrict__ f, uint* __restrict__ ftb,
            const float* __restrict__ W1, ushort* __restrict__ W1b,
            const float* __restrict__ W2, ushort* __restrict__ W2b,
            const float* __restrict__ xyz, const float* __restrict__ rot,
            int* __restrict__ idxp, float* __restrict__ gxp) {
  __shared__ float t[32][33];
  __shared__ int sidx[4][DNS];
  __shared__ float srot[4][9], sc[4][3];
  int blk = blockIdx.x;
  int tid = threadIdx.x;
  if (blk < 2048) {
    int ct = blk & 7, nt = (blk >> 3) & 31, b = blk >> 8;
    int tx = tid & 31, ty = tid >> 5;
#pragma unroll
    for (int k = 0; k < 4; ++k) {
      int c = ct * 32 + ty + k * 8;
      t[ty + k * 8][tx] = f[((size_t)b * DC + c) * DN + nt * 32 + tx];
    }
    __syncthreads();
    uint* dst = ftb + (size_t)b * DN * (DC / 2);
#pragma unroll
    for (int it = 0; it < 2; ++it) {
      int idx = it * 256 + tid;
      int nl = idx >> 4, cp = idx & 15;
      uint v = (uint)f2b(t[2 * cp][nl]) | ((uint)f2b(t[2 * cp + 1][nl]) << 16);
      dst[(size_t)(nt * 32 + nl) * (DC / 2) + ct * 16 + cp] = v;
    }
  } else if (blk < 2336) {
    int gid = (blk - 2048) * 256 + tid;
    if (gid < DC * K1) {
      int o = gid / K1, kp = gid - o * K1;
      float v = 0.f;
      if (kp < 256) v = W1[o * 259 + 3 + kp];
      else if (kp < 259) v = W1[o * 259 + (kp - 256)];
      W1b[gid] = f2b(v);
    }
  } else if (blk < 2592) {
    int gid = (blk - 2336) * 256 + tid;
    if (gid < DC * K2) W2b[gid] = f2b(W2[gid]);
  } else {
    int wv = tid >> 6;
    int lane = tid & 63;
    int bp = (blk - 2592) * 4 + wv;
    int b = bp >> 10;
    if (lane < DNS) sidx[wv][lane] = 0;
    if (lane < 9) srot[wv][lane] = rot[(size_t)bp * 9 + lane];
    if (lane < 3) sc[wv][lane] = xyz[(size_t)bp * 3 + lane];
    float r00 = srot[wv][0], r01 = srot[wv][1], r02 = srot[wv][2];
    float r10 = srot[wv][3], r11 = srot[wv][4], r12 = srot[wv][5];
    float r20 = srot[wv][6], r21 = srot[wv][7], r22 = srot[wv][8];
    float cx = sc[wv][0], cy = sc[wv][1], cz = sc[wv][2];
    const float* xb = xyz + (size_t)b * DN * 3;
    int cnt = 0;
    for (int ch = 0; ch < DN / 64 && cnt < DNS; ++ch) {
      int n = ch * 64 + lane;
      float dx = xb[n * 3 + 0] - cx, dy = xb[n * 3 + 1] - cy, dz = xb[n * 3 + 2] - cz;
      float lx = dx * r00 + dy * r10 + dz * r20;
      float ly = dx * r01 + dy * r11 + dz * r21;
      float lz = dx * r02 + dy * r12 + dz * r22;
      bool m = (ly * ly + lz * lz < kR2) && (lx > kHmin) && (lx < kHmax);
      unsigned long long bal = __ballot(m);
      int rank = cnt + __popcll(bal & ((1ull << lane) - 1ull));
      if (m && rank < DNS) sidx[wv][rank] = n;
      cnt += __popcll(bal);
    }
    if (lane < DNS) {
      int j = sidx[wv][lane];
      idxp[(size_t)bp * DNS + lane] = j;
      float gx = (xb[j * 3 + 0] - cx) / kRadius;
      float gy = (xb[j * 3 + 1] - cy) / kRadius;
      float gz = (xb[j * 3 + 2] - cz) / kRadius;
      float* gp = gxp + ((size_t)bp * DNS + lane) * 3;
      gp[0] = gx * r00 + gy * r10 + gz * r20;
      gp[1] = gx * r01 + gy * r11 + gz * r21;
      gp[2] = gx * r02 + gy * r12 + gz * r22;
    }
  }
}

// ---------------------------------------------------------------------------
// per-point counts + weighted gx sums via LDS histogram, plain-stored into
// per-block slices. 256 blocks x 256 thr (32 slices/batch, 1024 samples each).
// gg[blk*16+v]: v=0..5 gx 2nd moments, 6..8 gx sums.
__global__ __launch_bounds__(256)
void k_count(const int* __restrict__ idxp, const float* __restrict__ gxp,
             float* __restrict__ cntz, float* __restrict__ gwz,
             float* __restrict__ gg) {
  __shared__ float h0[DN], h1[DN], h2[DN], h3[DN];
  int t = threadIdx.x;
  int blk = blockIdx.x;          // 0..255; b = blk>>5, slice = blk&31
  for (int i = t; i < DN; i += 256) {
    h0[i] = 0.f; h1[i] = 0.f; h2[i] = 0.f; h3[i] = 0.f;
  }
  __syncthreads();
  float p[9] = {0.f, 0.f, 0.f, 0.f, 0.f, 0.f, 0.f, 0.f, 0.f};
#pragma unroll
  for (int r = 0; r < 4; ++r) {
    int sid = blk * 1024 + r * 256 + t;
    int j = idxp[sid];
    const float* g = gxp + (size_t)sid * 3;
    float g0 = g[0], g1 = g[1], g2 = g[2];
    atomicAdd(&h0[j], 1.f);
    atomicAdd(&h1[j], g0);
    atomicAdd(&h2[j], g1);
    atomicAdd(&h3[j], g2);
    p[0] += g0 * g0; p[1] += g0 * g1; p[2] += g0 * g2;
    p[3] += g1 * g1; p[4] += g1 * g2; p[5] += g2 * g2;
    p[6] += g0; p[7] += g1; p[8] += g2;
  }
  __syncthreads();
  for (int i = t; i < DN; i += 256) {
    cntz[(size_t)blk * DN + i] = h0[i];
    gwz[((size_t)blk * 3 + 0) * DN + i] = h1[i];
    gwz[((size_t)blk * 3 + 1) * DN + i] = h2[i];
    gwz[((size_t)blk * 3 + 2) * DN + i] = h3[i];
  }
  __shared__ float sgg[4][9];
#pragma unroll
  for (int v = 0; v < 9; ++v) {
    float sv = p[v];
#pragma unroll
    for (int m = 1; m < 64; m <<= 1) sv += __shfl_xor(sv, m, 64);
    if ((t & 63) == 0) sgg[t >> 6][v] = sv;
  }
  __syncthreads();
  if (t < 9) gg[blk * 16 + t] = sgg[0][t] + sgg[1][t] + sgg[2][t] + sgg[3][t];
}

// ---------------------------------------------------------------------------
// Yf = W1_feat x feats over unique points (K=256, no gather), fused weighted
// stats. 256 blocks x 256 thr: block = (row = b*8 + n-range) x (o-quarter).
__global__ __launch_bounds__(256)
void k_ygemm(const uint4* __restrict__ ftb, const ushort* __restrict__ W1b,
             const float* __restrict__ W1, const float* __restrict__ cntz,
             const float* __restrict__ gwz, float2* __restrict__ ypart) {
  __shared__ ushort x_lds[ROWS * XS];
  __shared__ float c_lds[ROWS];
  __shared__ float g_lds[3][ROWS];
  __shared__ float wg_lds[DC][3];

  const int nb = blockIdx.x;       // 0..255
  const int row = nb >> 2;         // 0..63
  const int oq = nb & 3;
  const int b = row >> 3;
  const int n0 = (row & 7) * ROWS;
  const int tid = threadIdx.x;
  const int lane = tid & 63;
  const int wv = tid >> 6;
  const int l15 = lane & 15;
  const int l4 = lane >> 4;

  {
    const uint4* src = ftb + ((size_t)b * DN + n0) * (DC / 8);
    for (int idx = tid; idx < ROWS * 32; idx += 256) {
      int rrow = idx >> 5, col = idx & 31;
      ((uint4*)(x_lds + (size_t)rrow * XS))[col] = src[rrow * 32 + col];
    }
  }
  if (tid < ROWS) {
    float c = 0.f, g0 = 0.f, g1 = 0.f, g2 = 0.f;
    for (int s = 0; s < NSL; ++s) {
      int blk = b * NSL + s;
      c += cntz[(size_t)blk * DN + n0 + tid];
      g0 += gwz[((size_t)blk * 3 + 0) * DN + n0 + tid];
      g1 += gwz[((size_t)blk * 3 + 1) * DN + n0 + tid];
      g2 += gwz[((size_t)blk * 3 + 2) * DN + n0 + tid];
    }
    c_lds[tid] = c; g_lds[0][tid] = g0; g_lds[1][tid] = g1; g_lds[2][tid] = g2;
  }
  {
    wg_lds[tid][0] = W1[tid * 259 + 0];
    wg_lds[tid][1] = W1[tid * 259 + 1];
    wg_lds[tid][2] = W1[tid * 259 + 2];
  }
  __syncthreads();

  f32x4 acc[8];
#pragma unroll
  for (int st = 0; st < 8; ++st)
#pragma unroll
    for (int r = 0; r < 4; ++r) acc[st][r] = 0.f;

  const int o0 = oq * 64 + wv * 16;
  const ushort* xbase = x_lds + (size_t)l15 * XS + l4 * 8;
  {
    const ushort* wrow = W1b + (size_t)(o0 + l15) * K1 + l4 * 8;
#pragma unroll
    for (int ks = 0; ks < 8; ++ks) {
      bf16x8 bx[8];
#pragma unroll
      for (int st = 0; st < 8; ++st)
        bx[st] = *(const bf16x8*)(xbase + (size_t)st * 16 * XS + ks * 32);
      bf16x8 aw = *(const bf16x8*)(wrow + ks * 32);
#pragma unroll
      for (int st = 0; st < 8; ++st)
        acc[st] = __builtin_amdgcn_mfma_f32_16x16x32_bf16(aw, bx[st],
                                                          acc[st], 0, 0, 0);
    }
  }

  float cn[8], h0[8], h1[8], h2[8];
#pragma unroll
  for (int st = 0; st < 8; ++st) {
    int n = st * 16 + l15;
    cn[st] = c_lds[n]; h0[st] = g_lds[0][n]; h1[st] = g_lds[1][n]; h2[st] = g_lds[2][n];
  }
#pragma unroll
  for (int r = 0; r < 4; ++r) {
    int o = o0 + l4 * 4 + r;
    float wg0 = wg_lds[o][0], wg1 = wg_lds[o][1], wg2 = wg_lds[o][2];
    float s = 0.f, q = 0.f;
#pragma unroll
    for (int st = 0; st < 8; ++st) {
      float Y = acc[st][r];
      float h = wg0 * h0[st] + wg1 * h1[st] + wg2 * h2[st];
      s = fmaf(cn[st], Y, s);
      q += cn[st] * Y * Y + 2.f * Y * h;
    }
#pragma unroll
    for (int m = 1; m < 16; m <<= 1) {
      s += __shfl_xor(s, m, 64);
      q += __shfl_xor(q, m, 64);
    }
    if (l15 == 0) ypart[(size_t)row * DC + o] = make_float2(s, q);
  }
}

// ---------------------------------------------------------------------------
__global__ __launch_bounds__(256)
void k_bn1f(const float2* __restrict__ ypart, const float* __restrict__ gg,
            const float* __restrict__ W1, const float* __restrict__ gam,
            const float* __restrict__ bet, float* __restrict__ bn) {
  __shared__ float ggs[9];
  int t = threadIdx.x;
  if (t < 9) {
    float s = 0.f;
    for (int blk = 0; blk < 256; ++blk) s += gg[blk * 16 + t];
    ggs[t] = s;
  }
  __syncthreads();
  float s = 0.f, q = 0.f;
  for (int nb = 0; nb < 64; ++nb) {
    float2 v = ypart[(size_t)nb * DC + t];
    s += v.x; q += v.y;
  }
  float wg0 = W1[t * 259 + 0], wg1 = W1[t * 259 + 1], wg2 = W1[t * 259 + 2];
  s += wg0 * ggs[6] + wg1 * ggs[7] + wg2 * ggs[8];
  q += wg0 * wg0 * ggs[0] + 2.f * wg0 * wg1 * ggs[1] + 2.f * wg0 * wg2 * ggs[2] +
       wg1 * wg1 * ggs[3] + 2.f * wg1 * wg2 * ggs[4] + wg2 * wg2 * ggs[5];
  float mu = s * kInvCnt;
  float var = q * kInvCnt - mu * mu;
  var = var < 0.f ? 0.f : var;
  float sc = gam[t] * rsqrtf(var + kEps);
  bn[t] = sc;
  bn[DC + t] = bet[t] - mu * sc;
}

// ---------------------------------------------------------------------------
// MFMA GEMM over 4 bp per block, 16x16x32 bf16 — 512 threads / 8 waves,
// r13 loops + XCD-aware bijective swizzle (r16/r17 measured best: ~88 us,
// VGPR 64 + 64 AGPR = exactly the 128-reg / 4-wave-per-SIMD cliff).
// ymax/ymin stored as bf16 (bit-exact: values come from the bf16 y-tile).
__global__ __launch_bounds__(512, 4)
void k_gemm_full(const uint4* __restrict__ ftb, const ushort* __restrict__ W1b,
                 const ushort* __restrict__ W2b, const int* __restrict__ idxp,
                 const float* __restrict__ gxp, const float* __restrict__ bn1,
                 float2* __restrict__ part, ushort* __restrict__ ymax,
                 ushort* __restrict__ ymin) {
  __shared__ ushort x_lds[ROWS * XS];   // 75776 B; also holds 128x258 y tile
  __shared__ float bn_lds[2 * DC];

  const int bid = blockIdx.x;
  const int grp = (bid & 7) * (NG / 8) + (bid >> 3);  // NG % 8 == 0: bijective
  const int bp0 = grp * 4;
  const int b = bp0 >> 10;
  const int tid = threadIdx.x;          // 0..511
  const int lane = tid & 63;
  const int wv = tid >> 6;              // 0..7
  const int l15 = lane & 15;
  const int l4 = lane >> 4;

  bn_lds[tid] = bn1[tid];               // 512 threads == 2*DC

  // ---- gather feats: 8 threads/row, 128-B coalesced segments, 2 passes ----
  {
    int q = tid & 7;
#pragma unroll
    for (int rep = 0; rep < 2; ++rep) {
      int s = (tid >> 3) + rep * 64;
      int j = idxp[(size_t)bp0 * DNS + s];
      const uint4* src = ftb + (size_t)(b * DN + j) * (DC / 8);
      uint4* dst = (uint4*)(x_lds + (size_t)s * XS);
#pragma unroll
      for (int k = 0; k < 4; ++k) dst[q + 8 * k] = src[q + 8 * k];
    }
  }
  // ---- gx channels at k=256..258, zeros to 287 ----
  if (tid < ROWS) {
    const float* g = gxp + ((size_t)bp0 * DNS + tid) * 3;
    uint a0 = (uint)f2b(g[0]) | ((uint)f2b(g[1]) << 16);
    uint a1 = (uint)f2b(g[2]);
    uint4* drow = (uint4*)(x_lds + (size_t)tid * XS + 256);
    drow[0] = make_uint4(a0, a1, 0u, 0u);
    drow[1] = make_uint4(0u, 0u, 0u, 0u);
    drow[2] = make_uint4(0u, 0u, 0u, 0u);
    drow[3] = make_uint4(0u, 0u, 0u, 0u);
  }
  __syncthreads();

  f32x4 acc[2][8];
#pragma unroll
  for (int t = 0; t < 2; ++t)
#pragma unroll
    for (int st = 0; st < 8; ++st)
#pragma unroll
      for (int r = 0; r < 4; ++r) acc[t][st][r] = 0.f;

  const int o0 = wv * 32;
  const ushort* xbase = x_lds + (size_t)l15 * XS + l4 * 8;

  // ---- GEMM1: K = 288, 9 K-steps of 32; A prefetched one step ahead ----
  {
    const ushort* wrow[2];
#pragma unroll
    for (int t = 0; t < 2; ++t)
      wrow[t] = W1b + (size_t)(o0 + t * 16 + l15) * K1 + l4 * 8;
    bf16x8 aw[2];
#pragma unroll
    for (int t = 0; t < 2; ++t) aw[t] = *(const bf16x8*)(wrow[t]);
#pragma unroll
    for (int ks = 0; ks < NK1; ++ks) {
      bf16x8 bx[8];
#pragma unroll
      for (int st = 0; st < 8; ++st)
        bx[st] = *(const bf16x8*)(xbase + (size_t)st * 16 * XS + ks * 32);
      bf16x8 an[2];
      if (ks + 1 < NK1) {
#pragma unroll
        for (int t = 0; t < 2; ++t)
          an[t] = *(const bf16x8*)(wrow[t] + (ks + 1) * 32);
      }
      __builtin_amdgcn_s_setprio(1);
#pragma unroll
      for (int st = 0; st < 8; ++st)
#pragma unroll
        for (int t = 0; t < 2; ++t)
          acc[t][st] = __builtin_amdgcn_mfma_f32_16x16x32_bf16(aw[t], bx[st],
                                                               acc[t][st], 0, 0, 0);
      __builtin_amdgcn_s_setprio(0);
      if (ks + 1 < NK1) {
#pragma unroll
        for (int t = 0; t < 2; ++t) aw[t] = an[t];
      }
    }
  }

  // ---- bn1 + relu -> x2 (bf16) back into x_lds[s][o] (stride XS) ----
  __syncthreads();  // all GEMM1 LDS reads complete before overwrite
#pragma unroll
  for (int t = 0; t < 2; ++t) {
    int ob = o0 + t * 16 + l4 * 4;
    float sc0 = bn_lds[ob + 0], sh0 = bn_lds[DC + ob + 0];
    float sc1 = bn_lds[ob + 1], sh1 = bn_lds[DC + ob + 1];
    float sc2 = bn_lds[ob + 2], sh2 = bn_lds[DC + ob + 2];
    float sc3 = bn_lds[ob + 3], sh3 = bn_lds[DC + ob + 3];
#pragma unroll
    for (int st = 0; st < 8; ++st) {
      float v0 = fmaxf(fmaf(acc[t][st][0], sc0, sh0), 0.f);
      float v1 = fmaxf(fmaf(acc[t][st][1], sc1, sh1), 0.f);
      float v2 = fmaxf(fmaf(acc[t][st][2], sc2, sh2), 0.f);
      float v3 = fmaxf(fmaf(acc[t][st][3], sc3, sh3), 0.f);
      uint2 pk = make_uint2((uint)f2b(v0) | ((uint)f2b(v1) << 16),
                            (uint)f2b(v2) | ((uint)f2b(v3) << 16));
      int s = st * 16 + l15;
      *(uint2*)(x_lds + (size_t)s * XS + ob) = pk;
      acc[t][st][0] = 0.f; acc[t][st][1] = 0.f;
      acc[t][st][2] = 0.f; acc[t][st][3] = 0.f;
    }
  }
  __syncthreads();

  // ---- GEMM2: K = 256, 8 K-steps; A prefetched one step ahead ----
  {
    const ushort* wrow[2];
#pragma unroll
    for (int t = 0; t < 2; ++t)
      wrow[t] = W2b + (size_t)(o0 + t * 16 + l15) * K2 + l4 * 8;
    bf16x8 aw[2];
#pragma unroll
    for (int t = 0; t < 2; ++t) aw[t] = *(const bf16x8*)(wrow[t]);
#pragma unroll
    for (int ks = 0; ks < NK2; ++ks) {
      bf16x8 bx[8];
#pragma unroll
      for (int st = 0; st < 8; ++st)
        bx[st] = *(const bf16x8*)(xbase + (size_t)st * 16 * XS + ks * 32);
      bf16x8 an[2];
      if (ks + 1 < NK2) {
#pragma unroll
        for (int t = 0; t < 2; ++t)
          an[t] = *(const bf16x8*)(wrow[t] + (ks + 1) * 32);
      }
      __builtin_amdgcn_s_setprio(1);
#pragma unroll
      for (int st = 0; st < 8; ++st)
#pragma unroll
        for (int t = 0; t < 2; ++t)
          acc[t][st] = __builtin_amdgcn_mfma_f32_16x16x32_bf16(aw[t], bx[st],
                                                               acc[t][st], 0, 0, 0);
      __builtin_amdgcn_s_setprio(0);
      if (ks + 1 < NK2) {
#pragma unroll
        for (int t = 0; t < 2; ++t) aw[t] = an[t];
      }
    }
  }

  // ---- y2 -> bf16 [s][o] tile, then per-o column stats + per-bp max/min ----
  __syncthreads();
#pragma unroll
  for (int t = 0; t < 2; ++t) {
    int ob = o0 + t * 16 + l4 * 4;
#pragma unroll
    for (int st = 0; st < 8; ++st) {
      uint2 pk = make_uint2(
          (uint)f2b(acc[t][st][0]) | ((uint)f2b(acc[t][st][1]) << 16),
          (uint)f2b(acc[t][st][2]) | ((uint)f2b(acc[t][st][3]) << 16));
      int s = st * 16 + l15;
      *(uint2*)(x_lds + (size_t)s * YS + ob) = pk;
    }
  }
  __syncthreads();
  {
    // partial-sum scratch in the free tail of x_lds (bytes 66048..70144)
    float* redp = (float*)(x_lds + (size_t)ROWS * YS);
    int o = tid & 255, half = tid >> 8;   // half: rows [half*64, half*64+64)
    const ushort* col = x_lds + o;
    float s = 0.f, q = 0.f;
#pragma unroll
    for (int p2 = 0; p2 < 2; ++p2) {
      int p = half * 2 + p2;              // bp index 0..3
      float mx = -3.4e38f, mn = 3.4e38f;
#pragma unroll 8
      for (int i = 0; i < DNS; ++i) {
        float v = b2f(col[(size_t)(p * DNS + i) * YS]);
        s += v; q += v * v;
        mx = fmaxf(mx, v); mn = fminf(mn, v);
      }
      ymax[(size_t)(bp0 + p) * DC + o] = f2b(mx);  // exact: mx is a bf16 value
      ymin[(size_t)(bp0 + p) * DC + o] = f2b(mn);
    }
    redp[half * 256 + o] = s;
    redp[512 + half * 256 + o] = q;
    __syncthreads();
    if (tid < 256) {
      float ss = redp[tid] + redp[256 + tid];
      float qq = redp[512 + tid] + redp[768 + tid];
      part[(size_t)grp * DC + tid] = make_float2(ss, qq);
    }
  }
}

// ---------------------------------------------------------------------------
__global__ void k_reduce_bn(const float* __restrict__ part, const float* __restrict__ gam,
                            const float* __restrict__ bet, float* __restrict__ bn) {
  int o = blockIdx.x, tid = threadIdx.x;
  __shared__ float ss[256], sq[256];
  float s = 0.f, q = 0.f;
  const float2* pp = (const float2*)part;
  for (int g = tid; g < NG; g += 256) {
    float2 v = pp[(size_t)g * DC + o];
    s += v.x; q += v.y;
  }
  ss[tid] = s; sq[tid] = q;
  __syncthreads();
  for (int w = 128; w > 0; w >>= 1) {
    if (tid < w) { ss[tid] += ss[tid + w]; sq[tid] += sq[tid + w]; }
    __syncthreads();
  }
  if (tid == 0) {
    float mu = ss[0] * kInvCnt;
    float var = sq[0] * kInvCnt - mu * mu;
    var = var < 0.f ? 0.f : var;
    float sc = gam[o] * rsqrtf(var + kEps);
    bn[o] = sc;
    bn[DC + o] = bet[o] - mu * sc;
  }
}

// ---------------------------------------------------------------------------
__global__ void k_final(const ushort* __restrict__ ymax, const ushort* __restrict__ ymin,
                        const float* __restrict__ bn2, float* __restrict__ out) {
  __shared__ float tmax[32][33], tmin[32][33];
  int ot = blockIdx.x, pt = blockIdx.y, b = blockIdx.z;
  int tx = threadIdx.x, ty = threadIdx.y;  // 32 x 8
#pragma unroll
  for (int k = 0; k < 4; ++k) {
    int pr = ty + k * 8;
    size_t base = ((size_t)(b * DP) + pt * 32 + pr) * DC + ot * 32 + tx;
    tmax[pr][tx] = b2f(ymax[base]);
    tmin[pr][tx] = b2f(ymin[base]);
  }
  __syncthreads();
#pragma unroll
  for (int k = 0; k < 4; ++k) {
    int oc = ty + k * 8;
    int o = ot * 32 + oc;
    float sc = bn2[o], sh = bn2[DC + o];
    float m = (sc >= 0.f) ? tmax[tx][oc] : tmin[tx][oc];
    float v = fmaf(sc, m, sh);
    v = v > 0.f ? v : 0.f;
    out[((size_t)(b * DC) + o) * DP + pt * 32 + tx] = v;
  }
}

// ---------------------------------------------------------------------------
extern "C" void kernel_launch(void* const* d_in, const int* in_sizes, int n_in,
                              void* d_out, int out_size, void* d_ws, size_t ws_size,
                              hipStream_t stream) {
  const float* xyz   = (const float*)d_in[0];
  const float* feats = (const float*)d_in[1];
  const float* rot   = (const float*)d_in[2];
  const float* W1    = (const float*)d_in[3];
  const float* g1    = (const float*)d_in[4];
  const float* b1    = (const float*)d_in[5];
  const float* W2    = (const float*)d_in[6];
  const float* g2    = (const float*)d_in[7];
  const float* b2    = (const float*)d_in[8];
  float* out = (float*)d_out;

  float* ws = (float*)d_ws;
  uint*   ftb_u  = (uint*)(ws + OF_FEATST);
  uint4*  ftb    = (uint4*)(ws + OF_FEATST);
  ushort* W1b    = (ushort*)(ws + OF_W1B);
  ushort* W2b    = (ushort*)(ws + OF_W2B);
  int*    idxp   = (int*)(ws + OF_IDX);
  float*  gxp    = ws + OF_GX;
  float2* partp  = (float2*)(ws + OF_PART);
  ushort* ymaxp  = (ushort*)(ws + OF_YMAX);
  ushort* yminp  = (ushort*)(ws + OF_YMIN);
  float*  bn1p   = ws + OF_BN1;
  float*  bn2p   = ws + OF_BN2;
  float*  cntzp  = ws + OF_CNTZ;   // aliased onto part/ymax region
  float*  gwzp   = ws + OF_GWZ;
  float*  ggp    = ws + OF_GG;
  float2* yprtp  = (float2*)(ws + OF_YPRT);

  k_prep<<<4640, 256, 0, stream>>>(feats, ftb_u, W1, W1b, W2, W2b,
                                   xyz, rot, idxp, gxp);

  // ---- bn1 stats via point-factored algebra (Y-GEMM over unique points) ----
  k_count<<<256, 256, 0, stream>>>(idxp, gxp, cntzp, gwzp, ggp);
  k_ygemm<<<256, 256, 0, stream>>>(ftb, W1b, W1, cntzp, gwzp, yprtp);
  k_bn1f<<<1, 256, 0, stream>>>(yprtp, ggp, W1, g1, b1, bn1p);

  // ---- fused GEMM1+bn1+relu+GEMM2 + y2 stats/max/min ----
  k_gemm_full<<<NG, 512, 0, stream>>>(ftb, W1b, W2b, idxp, gxp, bn1p, partp,
                                      ymaxp, yminp);
  k_reduce_bn<<<DC, 256, 0, stream>>>((const float*)partp, g2, b2, bn2p);
  k_final<<<dim3(DC / 32, DP / 32, DB), dim3(32, 8), 0, stream>>>(ymaxp, yminp, bn2p, out);
}

// Round 19
// 140.837 us; speedup vs baseline: 1.3053x; 1.0035x over previous
//
#include <hip/hip_runtime.h>
#include <hip/hip_bf16.h>

#define DB 8
#define DN 1024
#define DP 1024
#define DC 256
#define DNS 32
#define DBP (DB * DP)
#define K1 288   // padded ygemm K (256 feats; W1b rows also hold gx cols 256..258)
#define K2 256
#define XS 296   // k_ygemm x_lds row stride (ushorts)
#define XS2 264  // k_gemm_full x_lds row stride (528 B, 16B-aligned)
#define YS 258   // epilogue y-tile row stride in bf16
#define ROWS 128 // 4 bp per block
#define NG (DBP / 4)
#define NK2 (K2 / 32)  // 8
#define NSL 32   // cnt slices per batch (256 k_count blocks)

constexpr float kRadius = 0.05f;
constexpr float kR2 = kRadius * kRadius;
constexpr float kHmin = -0.02f;
constexpr float kHmax = 0.04f;
constexpr float kEps = 1e-5f;
constexpr float kInvCnt = 1.0f / (float)(DB * DP * DNS);

typedef __bf16 bf16x8 __attribute__((ext_vector_type(8)));
typedef float f32x4 __attribute__((ext_vector_type(4)));
static_assert(sizeof(bf16x8) == 16, "bf16x8 must be 16B");

// ---- workspace layout (in floats) ----
constexpr size_t OF_FEATST = 0;                                   // B*N*C bf16
constexpr size_t OF_W1B  = OF_FEATST + (size_t)DB * DN * DC / 2;  // DC*K1 bf16
constexpr size_t OF_W2B  = OF_W1B + (size_t)DC * K1 / 2;          // DC*K2 bf16
constexpr size_t OF_IDX  = OF_W2B + (size_t)DC * K2 / 2;          // BP*NS int32
constexpr size_t OF_GX   = OF_IDX + (size_t)DBP * DNS;            // BP*NS*3
constexpr size_t OF_PART = OF_GX + (size_t)DBP * DNS * 3;         // NG*C*2
constexpr size_t OF_YMAX = OF_PART + (size_t)NG * DC * 2;         // BP*C bf16
constexpr size_t OF_YMIN = OF_YMAX + (size_t)DBP * DC / 2;        // BP*C bf16
constexpr size_t OF_BN1  = OF_YMIN + (size_t)DBP * DC / 2;        // 5*DC (sc,sh,scw0..2)
constexpr size_t OF_BN2  = OF_BN1 + 1536;                         // 512
constexpr size_t OF_YFB  = OF_BN2 + 512;                          // B*N*DC bf16 (Yf rows)
// ---- stats scratch ALIASED onto part/ymax region (stats finish first) ----
constexpr size_t OF_CNTZ = OF_PART;                               // 256*DN
constexpr size_t OF_GWZ  = OF_CNTZ + (size_t)256 * DN;            // 256*3*DN
constexpr size_t OF_GG   = OF_GWZ + (size_t)256 * 3 * DN;         // 256*16
constexpr size_t OF_YPRT = OF_GG + 4096;                          // 64*DC*2

__device__ inline ushort f2b(float x) {
  union { __hip_bfloat16 h; ushort u; } c;
  c.h = __float2bfloat16(x);
  return c.u;
}
__device__ inline float b2f(ushort u) {
  union { uint u; float f; } c;
  c.u = (uint)u << 16;
  return c.f;
}

// ---------------------------------------------------------------------------
// fused pre-pass: [0,2048) transpose feats; [2048,2336) W1 prep; [2336,2592)
// W2 prep; [2592,4640) cylinder query (4 bp per block, one per wave).
__global__ __launch_bounds__(256)
void k_prep(const float* __restrict__ f, uint* __restrict__ ftb,
            const float* __restrict__ W1, ushort* __restrict__ W1b,
            const float* __restrict__ W2, ushort* __restrict__ W2b,
            const float* __restrict__ xyz, const float* __restrict__ rot,
            int* __restrict__ idxp, float* __restrict__ gxp) {
  __shared__ float t[32][33];
  __shared__ int sidx[4][DNS];
  __shared__ float srot[4][9], sc[4][3];
  int blk = blockIdx.x;
  int tid = threadIdx.x;
  if (blk < 2048) {
    int ct = blk & 7, nt = (blk >> 3) & 31, b = blk >> 8;
    int tx = tid & 31, ty = tid >> 5;
#pragma unroll
    for (int k = 0; k < 4; ++k) {
      int c = ct * 32 + ty + k * 8;
      t[ty + k * 8][tx] = f[((size_t)b * DC + c) * DN + nt * 32 + tx];
    }
    __syncthreads();
    uint* dst = ftb + (size_t)b * DN * (DC / 2);
#pragma unroll
    for (int it = 0; it < 2; ++it) {
      int idx = it * 256 + tid;
      int nl = idx >> 4, cp = idx & 15;
      uint v = (uint)f2b(t[2 * cp][nl]) | ((uint)f2b(t[2 * cp + 1][nl]) << 16);
      dst[(size_t)(nt * 32 + nl) * (DC / 2) + ct * 16 + cp] = v;
    }
  } else if (blk < 2336) {
    int gid = (blk - 2048) * 256 + tid;
    if (gid < DC * K1) {
      int o = gid / K1, kp = gid - o * K1;
      float v = 0.f;
      if (kp < 256) v = W1[o * 259 + 3 + kp];
      else if (kp < 259) v = W1[o * 259 + (kp - 256)];
      W1b[gid] = f2b(v);
    }
  } else if (blk < 2592) {
    int gid = (blk - 2336) * 256 + tid;
    if (gid < DC * K2) W2b[gid] = f2b(W2[gid]);
  } else {
    int wv = tid >> 6;
    int lane = tid & 63;
    int bp = (blk - 2592) * 4 + wv;
    int b = bp >> 10;
    if (lane < DNS) sidx[wv][lane] = 0;
    if (lane < 9) srot[wv][lane] = rot[(size_t)bp * 9 + lane];
    if (lane < 3) sc[wv][lane] = xyz[(size_t)bp * 3 + lane];
    float r00 = srot[wv][0], r01 = srot[wv][1], r02 = srot[wv][2];
    float r10 = srot[wv][3], r11 = srot[wv][4], r12 = srot[wv][5];
    float r20 = srot[wv][6], r21 = srot[wv][7], r22 = srot[wv][8];
    float cx = sc[wv][0], cy = sc[wv][1], cz = sc[wv][2];
    const float* xb = xyz + (size_t)b * DN * 3;
    int cnt = 0;
    for (int ch = 0; ch < DN / 64 && cnt < DNS; ++ch) {
      int n = ch * 64 + lane;
      float dx = xb[n * 3 + 0] - cx, dy = xb[n * 3 + 1] - cy, dz = xb[n * 3 + 2] - cz;
      float lx = dx * r00 + dy * r10 + dz * r20;
      float ly = dx * r01 + dy * r11 + dz * r21;
      float lz = dx * r02 + dy * r12 + dz * r22;
      bool m = (ly * ly + lz * lz < kR2) && (lx > kHmin) && (lx < kHmax);
      unsigned long long bal = __ballot(m);
      int rank = cnt + __popcll(bal & ((1ull << lane) - 1ull));
      if (m && rank < DNS) sidx[wv][rank] = n;
      cnt += __popcll(bal);
    }
    if (lane < DNS) {
      int j = sidx[wv][lane];
      idxp[(size_t)bp * DNS + lane] = j;
      float gx = (xb[j * 3 + 0] - cx) / kRadius;
      float gy = (xb[j * 3 + 1] - cy) / kRadius;
      float gz = (xb[j * 3 + 2] - cz) / kRadius;
      float* gp = gxp + ((size_t)bp * DNS + lane) * 3;
      gp[0] = gx * r00 + gy * r10 + gz * r20;
      gp[1] = gx * r01 + gy * r11 + gz * r21;
      gp[2] = gx * r02 + gy * r12 + gz * r22;
    }
  }
}

// ---------------------------------------------------------------------------
// per-point counts + weighted gx sums via LDS histogram, plain-stored into
// per-block slices. 256 blocks x 256 thr. gg[blk*16+v]: 0..5 moments, 6..8 sums.
__global__ __launch_bounds__(256)
void k_count(const int* __restrict__ idxp, const float* __restrict__ gxp,
             float* __restrict__ cntz, float* __restrict__ gwz,
             float* __restrict__ gg) {
  __shared__ float h0[DN], h1[DN], h2[DN], h3[DN];
  int t = threadIdx.x;
  int blk = blockIdx.x;
  for (int i = t; i < DN; i += 256) {
    h0[i] = 0.f; h1[i] = 0.f; h2[i] = 0.f; h3[i] = 0.f;
  }
  __syncthreads();
  float p[9] = {0.f, 0.f, 0.f, 0.f, 0.f, 0.f, 0.f, 0.f, 0.f};
#pragma unroll
  for (int r = 0; r < 4; ++r) {
    int sid = blk * 1024 + r * 256 + t;
    int j = idxp[sid];
    const float* g = gxp + (size_t)sid * 3;
    float g0 = g[0], g1 = g[1], g2 = g[2];
    atomicAdd(&h0[j], 1.f);
    atomicAdd(&h1[j], g0);
    atomicAdd(&h2[j], g1);
    atomicAdd(&h3[j], g2);
    p[0] += g0 * g0; p[1] += g0 * g1; p[2] += g0 * g2;
    p[3] += g1 * g1; p[4] += g1 * g2; p[5] += g2 * g2;
    p[6] += g0; p[7] += g1; p[8] += g2;
  }
  __syncthreads();
  for (int i = t; i < DN; i += 256) {
    cntz[(size_t)blk * DN + i] = h0[i];
    gwz[((size_t)blk * 3 + 0) * DN + i] = h1[i];
    gwz[((size_t)blk * 3 + 1) * DN + i] = h2[i];
    gwz[((size_t)blk * 3 + 2) * DN + i] = h3[i];
  }
  __shared__ float sgg[4][9];
#pragma unroll
  for (int v = 0; v < 9; ++v) {
    float sv = p[v];
#pragma unroll
    for (int m = 1; m < 64; m <<= 1) sv += __shfl_xor(sv, m, 64);
    if ((t & 63) == 0) sgg[t >> 6][v] = sv;
  }
  __syncthreads();
  if (t < 9) gg[blk * 16 + t] = sgg[0][t] + sgg[1][t] + sgg[2][t] + sgg[3][t];
}

// ---------------------------------------------------------------------------
// Yf = W1_feat x feats over unique points (K=256, no gather); stores Yf rows
// (bf16 [n][o]) for k_gemm_full's y1-gather AND the fused weighted stats.
// 256 blocks x 256 thr: block = (row = b*8 + n-range) x (o-quarter).
__global__ __launch_bounds__(256)
void k_ygemm(const uint4* __restrict__ ftb, const ushort* __restrict__ W1b,
             const float* __restrict__ W1, const float* __restrict__ cntz,
             const float* __restrict__ gwz, float2* __restrict__ ypart,
             ushort* __restrict__ yfb) {
  __shared__ ushort x_lds[ROWS * XS];
  __shared__ float c_lds[ROWS];
  __shared__ float g_lds[3][ROWS];
  __shared__ float wg_lds[DC][3];

  const int nb = blockIdx.x;       // 0..255
  const int row = nb >> 2;         // 0..63
  const int oq = nb & 3;
  const int b = row >> 3;
  const int n0 = (row & 7) * ROWS;
  const int tid = threadIdx.x;
  const int lane = tid & 63;
  const int wv = tid >> 6;
  const int l15 = lane & 15;
  const int l4 = lane >> 4;

  {
    const uint4* src = ftb + ((size_t)b * DN + n0) * (DC / 8);
    for (int idx = tid; idx < ROWS * 32; idx += 256) {
      int rrow = idx >> 5, col = idx & 31;
      ((uint4*)(x_lds + (size_t)rrow * XS))[col] = src[rrow * 32 + col];
    }
  }
  if (tid < ROWS) {
    float c = 0.f, g0 = 0.f, g1 = 0.f, g2 = 0.f;
    for (int s = 0; s < NSL; ++s) {
      int blk = b * NSL + s;
      c += cntz[(size_t)blk * DN + n0 + tid];
      g0 += gwz[((size_t)blk * 3 + 0) * DN + n0 + tid];
      g1 += gwz[((size_t)blk * 3 + 1) * DN + n0 + tid];
      g2 += gwz[((size_t)blk * 3 + 2) * DN + n0 + tid];
    }
    c_lds[tid] = c; g_lds[0][tid] = g0; g_lds[1][tid] = g1; g_lds[2][tid] = g2;
  }
  {
    wg_lds[tid][0] = W1[tid * 259 + 0];
    wg_lds[tid][1] = W1[tid * 259 + 1];
    wg_lds[tid][2] = W1[tid * 259 + 2];
  }
  __syncthreads();

  f32x4 acc[8];
#pragma unroll
  for (int st = 0; st < 8; ++st)
#pragma unroll
    for (int r = 0; r < 4; ++r) acc[st][r] = 0.f;

  const int o0 = oq * 64 + wv * 16;
  const ushort* xbase = x_lds + (size_t)l15 * XS + l4 * 8;
  {
    const ushort* wrow = W1b + (size_t)(o0 + l15) * K1 + l4 * 8;
#pragma unroll
    for (int ks = 0; ks < 8; ++ks) {
      bf16x8 bx[8];
#pragma unroll
      for (int st = 0; st < 8; ++st)
        bx[st] = *(const bf16x8*)(xbase + (size_t)st * 16 * XS + ks * 32);
      bf16x8 aw = *(const bf16x8*)(wrow + ks * 32);
#pragma unroll
      for (int st = 0; st < 8; ++st)
        acc[st] = __builtin_amdgcn_mfma_f32_16x16x32_bf16(aw, bx[st],
                                                          acc[st], 0, 0, 0);
    }
  }

  // ---- store Yf rows (bf16) for the y1-gather in k_gemm_full ----
  // lane holds Y[n = st*16+l15][o = o0 + l4*4 + r], r=0..3 -> one uint2.
#pragma unroll
  for (int st = 0; st < 8; ++st) {
    uint2 pk = make_uint2(
        (uint)f2b(acc[st][0]) | ((uint)f2b(acc[st][1]) << 16),
        (uint)f2b(acc[st][2]) | ((uint)f2b(acc[st][3]) << 16));
    int n = n0 + st * 16 + l15;
    *(uint2*)(yfb + ((size_t)b * DN + n) * DC + o0 + l4 * 4) = pk;
  }

  float cn[8], h0[8], h1[8], h2[8];
#pragma unroll
  for (int st = 0; st < 8; ++st) {
    int n = st * 16 + l15;
    cn[st] = c_lds[n]; h0[st] = g_lds[0][n]; h1[st] = g_lds[1][n]; h2[st] = g_lds[2][n];
  }
#pragma unroll
  for (int r = 0; r < 4; ++r) {
    int o = o0 + l4 * 4 + r;
    float wg0 = wg_lds[o][0], wg1 = wg_lds[o][1], wg2 = wg_lds[o][2];
    float s = 0.f, q = 0.f;
#pragma unroll
    for (int st = 0; st < 8; ++st) {
      float Y = acc[st][r];
      float h = wg0 * h0[st] + wg1 * h1[st] + wg2 * h2[st];
      s = fmaf(cn[st], Y, s);
      q += cn[st] * Y * Y + 2.f * Y * h;
    }
#pragma unroll
    for (int m = 1; m < 16; m <<= 1) {
      s += __shfl_xor(s, m, 64);
      q += __shfl_xor(q, m, 64);
    }
    if (l15 == 0) ypart[(size_t)row * DC + o] = make_float2(s, q);
  }
}

// ---------------------------------------------------------------------------
// bn1 params: sc, sh, and sc*wg (gx weights pre-scaled) for the y1-gather.
__global__ __launch_bounds__(256)
void k_bn1f(const float2* __restrict__ ypart, const float* __restrict__ gg,
            const float* __restrict__ W1, const float* __restrict__ gam,
            const float* __restrict__ bet, float* __restrict__ bn) {
  __shared__ float ggs[9];
  int t = threadIdx.x;
  if (t < 9) {
    float s = 0.f;
    for (int blk = 0; blk < 256; ++blk) s += gg[blk * 16 + t];
    ggs[t] = s;
  }
  __syncthreads();
  float s = 0.f, q = 0.f;
  for (int nb = 0; nb < 64; ++nb) {
    float2 v = ypart[(size_t)nb * DC + t];
    s += v.x; q += v.y;
  }
  float wg0 = W1[t * 259 + 0], wg1 = W1[t * 259 + 1], wg2 = W1[t * 259 + 2];
  s += wg0 * ggs[6] + wg1 * ggs[7] + wg2 * ggs[8];
  q += wg0 * wg0 * ggs[0] + 2.f * wg0 * wg1 * ggs[1] + 2.f * wg0 * wg2 * ggs[2] +
       wg1 * wg1 * ggs[3] + 2.f * wg1 * wg2 * ggs[4] + wg2 * wg2 * ggs[5];
  float mu = s * kInvCnt;
  float var = q * kInvCnt - mu * mu;
  var = var < 0.f ? 0.f : var;
  float sc = gam[t] * rsqrtf(var + kEps);
  bn[t] = sc;
  bn[DC + t] = bet[t] - mu * sc;
  bn[2 * DC + t] = sc * wg0;
  bn[3 * DC + t] = sc * wg1;
  bn[4 * DC + t] = sc * wg2;
}

// ---------------------------------------------------------------------------
// y1-gather + bn1 + relu -> x2 in LDS, then GEMM2 + stats/max/min.
// GEMM1 eliminated: x2[s][o] = relu(sc[o]*Yf[j_s][o] + scw[o].g_s + sh[o]).
// 512 threads / 8 waves; r13 GEMM2 loop; XCD-aware bijective swizzle.
__global__ __launch_bounds__(512, 4)
void k_gemm_full(const ushort* __restrict__ yfb, const ushort* __restrict__ W2b,
                 const int* __restrict__ idxp, const float* __restrict__ gxp,
                 const float* __restrict__ bn1, float2* __restrict__ part,
                 ushort* __restrict__ ymax, ushort* __restrict__ ymin) {
  __shared__ ushort x_lds[ROWS * XS2];  // 67584 B; also holds 128x258 y tile
  __shared__ float bnp[5 * DC];         // 5120 B: sc, sh, scw0, scw1, scw2
  __shared__ float redp[1024];          // 4096 B: part reduce scratch

  const int bid = blockIdx.x;
  const int grp = (bid & 7) * (NG / 8) + (bid >> 3);  // NG % 8 == 0: bijective
  const int bp0 = grp * 4;
  const int b = bp0 >> 10;
  const int tid = threadIdx.x;          // 0..511
  const int lane = tid & 63;
  const int wv = tid >> 6;              // 0..7
  const int l15 = lane & 15;
  const int l4 = lane >> 4;

  for (int i = tid; i < 5 * DC; i += 512) bnp[i] = bn1[i];
  __syncthreads();

  // ---- y1-gather + bn1 + relu -> x2 tile. 4 threads/row, 128-B segments ----
  {
    int s = tid >> 2, q = tid & 3;
    int j = idxp[(size_t)bp0 * DNS + s];
    const float* g = gxp + ((size_t)bp0 * DNS + s) * 3;
    float g0 = g[0], g1 = g[1], g2 = g[2];
    const uint4* yfr = (const uint4*)(yfb + ((size_t)b * DN + j) * DC) + q * 8;
    ushort* drow = x_lds + (size_t)s * XS2 + q * 64;
#pragma unroll
    for (int c = 0; c < 8; ++c) {
      uint4 v = yfr[c];
      int ob = q * 64 + c * 8;
      float4 scA = *(const float4*)&bnp[ob];
      float4 scB = *(const float4*)&bnp[ob + 4];
      float4 shA = *(const float4*)&bnp[DC + ob];
      float4 shB = *(const float4*)&bnp[DC + ob + 4];
      float4 w0A = *(const float4*)&bnp[2 * DC + ob];
      float4 w0B = *(const float4*)&bnp[2 * DC + ob + 4];
      float4 w1A = *(const float4*)&bnp[3 * DC + ob];
      float4 w1B = *(const float4*)&bnp[3 * DC + ob + 4];
      float4 w2A = *(const float4*)&bnp[4 * DC + ob];
      float4 w2B = *(const float4*)&bnp[4 * DC + ob + 4];
      float y0 = b2f((ushort)(v.x & 0xffff)), y1 = b2f((ushort)(v.x >> 16));
      float y2 = b2f((ushort)(v.y & 0xffff)), y3 = b2f((ushort)(v.y >> 16));
      float y4 = b2f((ushort)(v.z & 0xffff)), y5 = b2f((ushort)(v.z >> 16));
      float y6 = b2f((ushort)(v.w & 0xffff)), y7 = b2f((ushort)(v.w >> 16));
      float r0 = fmaxf(fmaf(scA.x, y0, fmaf(w0A.x, g0, fmaf(w1A.x, g1, fmaf(w2A.x, g2, shA.x)))), 0.f);
      float r1 = fmaxf(fmaf(scA.y, y1, fmaf(w0A.y, g0, fmaf(w1A.y, g1, fmaf(w2A.y, g2, shA.y)))), 0.f);
      float r2 = fmaxf(fmaf(scA.z, y2, fmaf(w0A.z, g0, fmaf(w1A.z, g1, fmaf(w2A.z, g2, shA.z)))), 0.f);
      float r3 = fmaxf(fmaf(scA.w, y3, fmaf(w0A.w, g0, fmaf(w1A.w, g1, fmaf(w2A.w, g2, shA.w)))), 0.f);
      float r4 = fmaxf(fmaf(scB.x, y4, fmaf(w0B.x, g0, fmaf(w1B.x, g1, fmaf(w2B.x, g2, shB.x)))), 0.f);
      float r5 = fmaxf(fmaf(scB.y, y5, fmaf(w0B.y, g0, fmaf(w1B.y, g1, fmaf(w2B.y, g2, shB.y)))), 0.f);
      float r6 = fmaxf(fmaf(scB.z, y6, fmaf(w0B.z, g0, fmaf(w1B.z, g1, fmaf(w2B.z, g2, shB.z)))), 0.f);
      float r7 = fmaxf(fmaf(scB.w, y7, fmaf(w0B.w, g0, fmaf(w1B.w, g1, fmaf(w2B.w, g2, shB.w)))), 0.f);
      uint4 pk;
      pk.x = (uint)f2b(r0) | ((uint)f2b(r1) << 16);
      pk.y = (uint)f2b(r2) | ((uint)f2b(r3) << 16);
      pk.z = (uint)f2b(r4) | ((uint)f2b(r5) << 16);
      pk.w = (uint)f2b(r6) | ((uint)f2b(r7) << 16);
      *(uint4*)(drow + c * 8) = pk;
    }
  }
  __syncthreads();

  f32x4 acc[2][8];
#pragma unroll
  for (int t = 0; t < 2; ++t)
#pragma unroll
    for (int st = 0; st < 8; ++st)
#pragma unroll
      for (int r = 0; r < 4; ++r) acc[t][st][r] = 0.f;

  const int o0 = wv * 32;
  const ushort* xbase = x_lds + (size_t)l15 * XS2 + l4 * 8;

  // ---- GEMM2: K = 256, 8 K-steps; A prefetched one step ahead ----
  {
    const ushort* wrow[2];
#pragma unroll
    for (int t = 0; t < 2; ++t)
      wrow[t] = W2b + (size_t)(o0 + t * 16 + l15) * K2 + l4 * 8;
    bf16x8 aw[2];
#pragma unroll
    for (int t = 0; t < 2; ++t) aw[t] = *(const bf16x8*)(wrow[t]);
#pragma unroll
    for (int ks = 0; ks < NK2; ++ks) {
      bf16x8 bx[8];
#pragma unroll
      for (int st = 0; st < 8; ++st)
        bx[st] = *(const bf16x8*)(xbase + (size_t)st * 16 * XS2 + ks * 32);
      bf16x8 an[2];
      if (ks + 1 < NK2) {
#pragma unroll
        for (int t = 0; t < 2; ++t)
          an[t] = *(const bf16x8*)(wrow[t] + (ks + 1) * 32);
      }
      __builtin_amdgcn_s_setprio(1);
#pragma unroll
      for (int st = 0; st < 8; ++st)
#pragma unroll
        for (int t = 0; t < 2; ++t)
          acc[t][st] = __builtin_amdgcn_mfma_f32_16x16x32_bf16(aw[t], bx[st],
                                                               acc[t][st], 0, 0, 0);
      __builtin_amdgcn_s_setprio(0);
      if (ks + 1 < NK2) {
#pragma unroll
        for (int t = 0; t < 2; ++t) aw[t] = an[t];
      }
    }
  }

  // ---- y2 -> bf16 [s][o] tile, then per-o column stats + per-bp max/min ----
  __syncthreads();
#pragma unroll
  for (int t = 0; t < 2; ++t) {
    int ob = o0 + t * 16 + l4 * 4;
#pragma unroll
    for (int st = 0; st < 8; ++st) {
      uint2 pk = make_uint2(
          (uint)f2b(acc[t][st][0]) | ((uint)f2b(acc[t][st][1]) << 16),
          (uint)f2b(acc[t][st][2]) | ((uint)f2b(acc[t][st][3]) << 16));
      int s = st * 16 + l15;
      *(uint2*)(x_lds + (size_t)s * YS + ob) = pk;
    }
  }
  __syncthreads();
  {
    int o = tid & 255, half = tid >> 8;   // half: rows [half*64, half*64+64)
    const ushort* col = x_lds + o;
    float s = 0.f, q = 0.f;
#pragma unroll
    for (int p2 = 0; p2 < 2; ++p2) {
      int p = half * 2 + p2;              // bp index 0..3
      float mx = -3.4e38f, mn = 3.4e38f;
#pragma unroll 8
      for (int i = 0; i < DNS; ++i) {
        float v = b2f(col[(size_t)(p * DNS + i) * YS]);
        s += v; q += v * v;
        mx = fmaxf(mx, v); mn = fminf(mn, v);
      }
      ymax[(size_t)(bp0 + p) * DC + o] = f2b(mx);  // exact: mx is a bf16 value
      ymin[(size_t)(bp0 + p) * DC + o] = f2b(mn);
    }
    redp[half * 256 + o] = s;
    redp[512 + half * 256 + o] = q;
    __syncthreads();
    if (tid < 256) {
      float ss = redp[tid] + redp[256 + tid];
      float qq = redp[512 + tid] + redp[768 + tid];
      part[(size_t)grp * DC + tid] = make_float2(ss, qq);
    }
  }
}

// ---------------------------------------------------------------------------
__global__ void k_reduce_bn(const float* __restrict__ part, const float* __restrict__ gam,
                            const float* __restrict__ bet, float* __restrict__ bn) {
  int o = blockIdx.x, tid = threadIdx.x;
  __shared__ float ss[256], sq[256];
  float s = 0.f, q = 0.f;
  const float2* pp = (const float2*)part;
  for (int g = tid; g < NG; g += 256) {
    float2 v = pp[(size_t)g * DC + o];
    s += v.x; q += v.y;
  }
  ss[tid] = s; sq[tid] = q;
  __syncthreads();
  for (int w = 128; w > 0; w >>= 1) {
    if (tid < w) { ss[tid] += ss[tid + w]; sq[tid] += sq[tid + w]; }
    __syncthreads();
  }
  if (tid == 0) {
    float mu = ss[0] * kInvCnt;
    float var = sq[0] * kInvCnt - mu * mu;
    var = var < 0.f ? 0.f : var;
    float sc = gam[o] * rsqrtf(var + kEps);
    bn[o] = sc;
    bn[DC + o] = bet[o] - mu * sc;
  }
}

// ---------------------------------------------------------------------------
__global__ void k_final(const ushort* __restrict__ ymax, const ushort* __restrict__ ymin,
                        const float* __restrict__ bn2, float* __restrict__ out) {
  __shared__ float tmax[32][33], tmin[32][33];
  int ot = blockIdx.x, pt = blockIdx.y, b = blockIdx.z;
  int tx = threadIdx.x, ty = threadIdx.y;  // 32 x 8
#pragma unroll
  for (int k = 0; k < 4; ++k) {
    int pr = ty + k * 8;
    size_t base = ((size_t)(b * DP) + pt * 32 + pr) * DC + ot * 32 + tx;
    tmax[pr][tx] = b2f(ymax[base]);
    tmin[pr][tx] = b2f(ymin[base]);
  }
  __syncthreads();
#pragma unroll
  for (int k = 0; k < 4; ++k) {
    int oc = ty + k * 8;
    int o = ot * 32 + oc;
    float sc = bn2[o], sh = bn2[DC + o];
    float m = (sc >= 0.f) ? tmax[tx][oc] : tmin[tx][oc];
    float v = fmaf(sc, m, sh);
    v = v > 0.f ? v : 0.f;
    out[((size_t)(b * DC) + o) * DP + pt * 32 + tx] = v;
  }
}

// ---------------------------------------------------------------------------
extern "C" void kernel_launch(void* const* d_in, const int* in_sizes, int n_in,
                              void* d_out, int out_size, void* d_ws, size_t ws_size,
                              hipStream_t stream) {
  const float* xyz   = (const float*)d_in[0];
  const float* feats = (const float*)d_in[1];
  const float* rot   = (const float*)d_in[2];
  const float* W1    = (const float*)d_in[3];
  const float* g1    = (const float*)d_in[4];
  const float* b1    = (const float*)d_in[5];
  const float* W2    = (const float*)d_in[6];
  const float* g2    = (const float*)d_in[7];
  const float* b2    = (const float*)d_in[8];
  float* out = (float*)d_out;

  float* ws = (float*)d_ws;
  uint*   ftb_u  = (uint*)(ws + OF_FEATST);
  uint4*  ftb    = (uint4*)(ws + OF_FEATST);
  ushort* W1b    = (ushort*)(ws + OF_W1B);
  ushort* W2b    = (ushort*)(ws + OF_W2B);
  int*    idxp   = (int*)(ws + OF_IDX);
  float*  gxp    = ws + OF_GX;
  float2* partp  = (float2*)(ws + OF_PART);
  ushort* ymaxp  = (ushort*)(ws + OF_YMAX);
  ushort* yminp  = (ushort*)(ws + OF_YMIN);
  float*  bn1p   = ws + OF_BN1;
  float*  bn2p   = ws + OF_BN2;
  ushort* yfbp   = (ushort*)(ws + OF_YFB);
  float*  cntzp  = ws + OF_CNTZ;   // aliased onto part/ymax region
  float*  gwzp   = ws + OF_GWZ;
  float*  ggp    = ws + OF_GG;
  float2* yprtp  = (float2*)(ws + OF_YPRT);

  k_prep<<<4640, 256, 0, stream>>>(feats, ftb_u, W1, W1b, W2, W2b,
                                   xyz, rot, idxp, gxp);

  // ---- bn1 stats + Yf rows via point-factored algebra ----
  k_count<<<256, 256, 0, stream>>>(idxp, gxp, cntzp, gwzp, ggp);
  k_ygemm<<<256, 256, 0, stream>>>(ftb, W1b, W1, cntzp, gwzp, yprtp, yfbp);
  k_bn1f<<<1, 256, 0, stream>>>(yprtp, ggp, W1, g1, b1, bn1p);

  // ---- y1-gather + bn1 + relu + GEMM2 + y2 stats/max/min ----
  k_gemm_full<<<NG, 512, 0, stream>>>(yfbp, W2b, idxp, gxp, bn1p, partp,
                                      ymaxp, yminp);
  k_reduce_bn<<<DC, 256, 0, stream>>>((const float*)partp, g2, b2, bn2p);
  k_final<<<dim3(DC / 32, DP / 32, DB), dim3(32, 8), 0, stream>>>(ymaxp, yminp, bn2p, out);
}